// Round 10
// baseline (489.989 us; speedup 1.0000x reference)
//
#include <hip/hip_runtime.h>
#include <cstddef>

// GCN encoder, BN-folded formulation, gather fused into consumer GEMMs.
// prop(h)[d] = dinv[d]*(P(h)[d] @ W) + b, P(h)[d] = sum_{s in N(d)+self} dinv[s]*h[s].
// BN(z) = z*sc + sh  =>  P(BN(o))[d] = sc (.) P(o)[d] + q[d]*sh, q graph-only.
// Each layer's GEMM gathers its 64-row tile G = gather(Z) (Z = o*dinv) straight
// into LDS via CSR, uses W' = diag(sc)@W, c' = sh@W, epilogue
// u = dv*acc + dv*q[r]*c'[c] + b[c]. BN stats accumulate in the epilogue.

#define NEG_SLOPE 0.01f
#define BN_EPS 1e-5f

__global__ __launch_bounds__(256) void init_k(int* __restrict__ cnt,
                                              float* __restrict__ bns, int N) {
  int i = blockIdx.x * 256 + threadIdx.x;
  if (i < N) cnt[i] = 0;
  if (i < 384) bns[i] = 0.0f;  // 3 layers x {sum[64], sumsq[64]}
}

__global__ __launch_bounds__(256) void hist_k(const int* __restrict__ dst,
                                              int* __restrict__ cnt, int E) {
  int e = blockIdx.x * 256 + threadIdx.x;
  if (e < E) atomicAdd(&cnt[dst[e]], 1);
}

// Multi-block scan, phase A: block-local exclusive scan of cnt into pre
// (=rowptr used as scratch), block totals into bsum.
__global__ __launch_bounds__(1024) void scanA(const int* __restrict__ cnt,
                                              int* __restrict__ pre,
                                              int* __restrict__ bsum, int N) {
  __shared__ int sh[1024];
  const int t = threadIdx.x;
  const int i = blockIdx.x * 1024 + t;
  int c = (i < N) ? cnt[i] : 0;
  sh[t] = c;
  __syncthreads();
  for (int off = 1; off < 1024; off <<= 1) {
    int v = (t >= off) ? sh[t - off] : 0;
    __syncthreads();
    sh[t] += v;
    __syncthreads();
  }
  if (i < N) pre[i] = sh[t] - c;  // exclusive
  if (t == 1023) bsum[blockIdx.x] = sh[t];
}

// Phase B: single-wave exclusive scan of nb (<=64) block sums in place.
__global__ __launch_bounds__(64) void scanB(int* __restrict__ bsum, int nb) {
  int t = threadIdx.x;
  int orig = (t < nb) ? bsum[t] : 0;
  int v = orig;
#pragma unroll
  for (int off = 1; off < 64; off <<= 1) {
    int u = __shfl_up(v, off);
    if (t >= off) v += u;
  }
  if (t < nb) bsum[t] = v - orig;
}

// Phase C: rowptr = pre + bsum[blk]; cursor copy; dinv = rsqrt(deg+1).
__global__ __launch_bounds__(256) void scanC(const int* __restrict__ cnt,
                                             int* __restrict__ rowptr,
                                             int* __restrict__ cursor,
                                             const int* __restrict__ bsum,
                                             float* __restrict__ dinv,
                                             int N, int E) {
  int i = blockIdx.x * 256 + threadIdx.x;
  if (i < N) {
    int rp = rowptr[i] + bsum[i >> 10];
    rowptr[i] = rp;
    cursor[i] = rp;
    dinv[i] = rsqrtf((float)(cnt[i] + 1));  // +1 self loop
  }
  if (i == 0) rowptr[N] = E;
}

__global__ __launch_bounds__(256) void fill_k(const int* __restrict__ src,
                                              const int* __restrict__ dst,
                                              int* __restrict__ cursor,
                                              int* __restrict__ eidx, int E) {
  int e = blockIdx.x * 256 + threadIdx.x;
  if (e >= E) return;
  int p = atomicAdd(&cursor[dst[e]], 1);
  eidx[p] = src[e];
}

// Layer 1 fully fused: per node (one wave, grid-stride):
//   agg(3ch) = x[node]*dv + sum_e x[src]*dinv[src];  q[node] = dv + sum dinv[src]
//   u = dv*(agg @ W1) + b1; o = LeakyReLU(u); Z1 = o*dv; BN stats of o.
__global__ __launch_bounds__(256) void l1_fused(
    const int* __restrict__ rowptr, const int* __restrict__ eidx,
    const float* __restrict__ x, const float* __restrict__ dinv,
    const float* __restrict__ W1, const float* __restrict__ b1,
    float* __restrict__ Z, float* __restrict__ q, float* __restrict__ bns, int N) {
  const int t = threadIdx.x, lane = t & 63, wid = t >> 6;
  const int gw = blockIdx.x * 4 + wid;
  const int nw = gridDim.x * 4;
  const float w0 = W1[lane], w1 = W1[64 + lane], w2 = W1[128 + lane];
  const float bb = b1[lane];
  float s1 = 0.f, s2 = 0.f;
  for (int node = gw; node < N; node += nw) {
    int beg = rowptr[node], end = rowptr[node + 1];
    float a0 = 0.f, a1 = 0.f, a2 = 0.f, aq = 0.f;
    for (int e = beg + lane; e < end; e += 64) {
      int s = eidx[e];
      float dv = dinv[s];
      a0 += x[s * 3] * dv;
      a1 += x[s * 3 + 1] * dv;
      a2 += x[s * 3 + 2] * dv;
      aq += dv;
    }
#pragma unroll
    for (int off = 32; off; off >>= 1) {
      a0 += __shfl_xor(a0, off);
      a1 += __shfl_xor(a1, off);
      a2 += __shfl_xor(a2, off);
      aq += __shfl_xor(aq, off);
    }
    float dv = dinv[node];
    a0 += x[node * 3] * dv;
    a1 += x[node * 3 + 1] * dv;
    a2 += x[node * 3 + 2] * dv;
    aq += dv;
    float u = dv * (a0 * w0 + a1 * w1 + a2 * w2) + bb;
    float o = u >= 0.f ? u : NEG_SLOPE * u;
    Z[(size_t)node * 64 + lane] = o * dv;
    s1 += o;
    s2 += o * o;
    if (lane == 0) q[node] = aq;
  }
  __shared__ float red[8][64];
  red[wid][lane] = s1;
  red[4 + wid][lane] = s2;
  __syncthreads();
  if (t < 64) {
    atomicAdd(&bns[t], red[0][t] + red[1][t] + red[2][t] + red[3][t]);
    atomicAdd(&bns[64 + t], red[4][t] + red[5][t] + red[6][t] + red[7][t]);
  }
}

// In-block CSR gather of a 64-row tile into LDS P. Wave w handles rows
// [w*16, w*16+16); lane = (slot: lane>>4) x (4 ch: (lane&15)*4); 4 edges/iter
// unroll 2 -> 8 edges in flight; shfl_xor(16|32) cross-slot reduce.
__device__ __forceinline__ void gather_tile(
    const int* __restrict__ rowptr, const int* __restrict__ eidx,
    const float* __restrict__ Z, float (*__restrict__ P)[68], int r0, int N) {
  const int t = threadIdx.x;
  const int lane = t & 63, wid = t >> 6;
  const int slot = lane >> 4, c4 = (lane & 15) << 2;
#pragma unroll 1
  for (int i = 0; i < 16; ++i) {
    const int r = wid * 16 + i;
    const int gr = r0 + r;
    float ax = 0.f, ay = 0.f, az = 0.f, aw = 0.f;
    if (gr < N) {
      const int beg = rowptr[gr], end = rowptr[gr + 1];
      int e = beg + slot;
      for (; e + 4 < end; e += 8) {
        int s0 = eidx[e], s1 = eidx[e + 4];
        float4 v0 = *(const float4*)(Z + (size_t)s0 * 64 + c4);
        float4 v1 = *(const float4*)(Z + (size_t)s1 * 64 + c4);
        ax += v0.x + v1.x;
        ay += v0.y + v1.y;
        az += v0.z + v1.z;
        aw += v0.w + v1.w;
      }
      if (e < end) {
        int s0 = eidx[e];
        float4 v0 = *(const float4*)(Z + (size_t)s0 * 64 + c4);
        ax += v0.x; ay += v0.y; az += v0.z; aw += v0.w;
      }
    }
#pragma unroll
    for (int off = 16; off < 64; off <<= 1) {
      ax += __shfl_xor(ax, off);
      ay += __shfl_xor(ay, off);
      az += __shfl_xor(az, off);
      aw += __shfl_xor(aw, off);
    }
    if (slot == 0) {
      float4 o = make_float4(0.f, 0.f, 0.f, 0.f);
      if (gr < N) {
        float4 self = *(const float4*)(Z + (size_t)gr * 64 + c4);
        o = make_float4(ax + self.x, ay + self.y, az + self.z, aw + self.w);
      }
      *(float4*)&P[r][c4] = o;
    }
  }
}

// sc/sh from bns, then W'[k][c] = sc[k]*W[k][c] (64x64), c'[c] = sum_k sh[k]*W[k][c].
__global__ __launch_bounds__(256) void prep_small(
    const float* __restrict__ bns, const float* __restrict__ g,
    const float* __restrict__ be, const float* __restrict__ W,
    float* __restrict__ Wc, float* __restrict__ cx, float invN) {
  __shared__ float sc[64], sh[64], part[4][64];
  int t = threadIdx.x;
  if (t < 64) {
    float mean = bns[t] * invN;
    float var = bns[64 + t] * invN - mean * mean;
    float s = g[t] * rsqrtf(var + BN_EPS);
    sc[t] = s;
    sh[t] = be[t] - mean * s;
  }
  __syncthreads();
  int c = t & 63, kq = t >> 6;
  float p = 0.f;
  for (int k = kq * 16; k < kq * 16 + 16; ++k) {
    float w = W[k * 64 + c];
    Wc[k * 64 + c] = sc[k] * w;
    p += sh[k] * w;
  }
  part[kq][c] = p;
  __syncthreads();
  if (t < 64) cx[t] = part[0][t] + part[1][t] + part[2][t] + part[3][t];
}

// Same for the two 64x768 head weights. grid.x = 12: 0-5 mu, 6-11 ls (128 cols each).
__global__ __launch_bounds__(256) void prep_head(
    const float* __restrict__ bns, const float* __restrict__ g,
    const float* __restrict__ be, const float* __restrict__ Wmu,
    const float* __restrict__ Wls, float* __restrict__ Wmc,
    float* __restrict__ Wlc, float* __restrict__ cmu, float* __restrict__ cls,
    float invN) {
  __shared__ float sc[64], sh[64], part[2][128];
  int t = threadIdx.x;
  if (t < 64) {
    float mean = bns[t] * invN;
    float var = bns[64 + t] * invN - mean * mean;
    float s = g[t] * rsqrtf(var + BN_EPS);
    sc[t] = s;
    sh[t] = be[t] - mean * s;
  }
  __syncthreads();
  int blk = blockIdx.x;
  int head = blk >= 6 ? 1 : 0;
  int c0 = (head ? blk - 6 : blk) * 128;
  const float* W = head ? Wls : Wmu;
  float* Wc = head ? Wlc : Wmc;
  float* cx = head ? cls : cmu;
  int c = c0 + (t & 127), kh = t >> 7;
  float p = 0.f;
  for (int k = kh * 32; k < kh * 32 + 32; ++k) {
    float w = W[(size_t)k * 768 + c];
    Wc[(size_t)k * 768 + c] = sc[k] * w;
    p += sh[k] * w;
  }
  part[kh][t & 127] = p;
  __syncthreads();
  if (t < 128) cx[c0 + t] = part[0][t] + part[1][t];
}

// Layers 2/3: gather tile in-block, then
// Z_next = LeakyReLU(dv*(P @ Wc) + dv*q[r]*cx + b) * dv, plus BN stats of o.
__global__ __launch_bounds__(256, 4) void gemm_bnq_f(
    const int* __restrict__ rowptr, const int* __restrict__ eidx,
    const float* __restrict__ Zin, const float* __restrict__ dinv,
    const float* __restrict__ q, const float* __restrict__ Wc,
    const float* __restrict__ cx, const float* __restrict__ b,
    float* __restrict__ Z, float* __restrict__ bns, int N) {
  __shared__ __align__(16) float P[64][68];
  __shared__ __align__(16) float Ws[64][64];
  const int t = threadIdx.x;
  const int r0 = blockIdx.x * 64;

  for (int i = t; i < 4096; i += 256) Ws[i >> 6][i & 63] = Wc[i];
  gather_tile(rowptr, eidx, Zin, P, r0, N);
  __syncthreads();

  const int tr = t >> 4, tc4 = (t & 15) << 2;
  float acc[4][4] = {};
#pragma unroll 8
  for (int k = 0; k < 64; ++k) {
    float4 w = *(const float4*)&Ws[k][tc4];
#pragma unroll
    for (int i = 0; i < 4; ++i) {
      float a = P[tr + 16 * i][k];
      acc[i][0] += a * w.x;
      acc[i][1] += a * w.y;
      acc[i][2] += a * w.z;
      acc[i][3] += a * w.w;
    }
  }

  float s1[4] = {0.f, 0.f, 0.f, 0.f}, s2[4] = {0.f, 0.f, 0.f, 0.f};
  float4 bb = *(const float4*)(b + tc4);
  float4 cc = *(const float4*)(cx + tc4);
#pragma unroll
  for (int i = 0; i < 4; ++i) {
    int r = r0 + tr + 16 * i;
    if (r < N) {
      float dv = dinv[r];
      float dq = dv * q[r];
      float u0 = acc[i][0] * dv + dq * cc.x + bb.x;
      float u1 = acc[i][1] * dv + dq * cc.y + bb.y;
      float u2 = acc[i][2] * dv + dq * cc.z + bb.z;
      float u3 = acc[i][3] * dv + dq * cc.w + bb.w;
      float o0 = u0 >= 0.f ? u0 : NEG_SLOPE * u0;
      float o1 = u1 >= 0.f ? u1 : NEG_SLOPE * u1;
      float o2 = u2 >= 0.f ? u2 : NEG_SLOPE * u2;
      float o3 = u3 >= 0.f ? u3 : NEG_SLOPE * u3;
      float4 z = make_float4(o0 * dv, o1 * dv, o2 * dv, o3 * dv);
      *(float4*)(Z + (size_t)r * 64 + tc4) = z;
      s1[0] += o0; s2[0] += o0 * o0;
      s1[1] += o1; s2[1] += o1 * o1;
      s1[2] += o2; s2[2] += o2 * o2;
      s1[3] += o3; s2[3] += o3 * o3;
    }
  }
  __syncthreads();  // Ws no longer needed; reuse for BN reduction
  float (*red1)[64] = (float(*)[64]) & Ws[0][0];
  float (*red2)[64] = (float(*)[64]) & Ws[16][0];
#pragma unroll
  for (int j = 0; j < 4; ++j) {
    red1[tr][tc4 + j] = s1[j];
    red2[tr][tc4 + j] = s2[j];
  }
  __syncthreads();
  if (t < 64) {
    float a1 = 0.f, a2 = 0.f;
#pragma unroll
    for (int i = 0; i < 16; ++i) {
      a1 += red1[i][t];
      a2 += red2[i][t];
    }
    atomicAdd(&bns[t], a1);
    atomicAdd(&bns[64 + t], a2);
  }
}

// Heads: gather the 64-row tile ONCE, then loop all 12 col-chunks
// (0-5 mu, 6-11 ls; 128 cols each). out = dv*(P @ Wc) + dv*q[r]*cx + b.
__global__ __launch_bounds__(256, 4) void head_f(
    const int* __restrict__ rowptr, const int* __restrict__ eidx,
    const float* __restrict__ Zin, const float* __restrict__ dinv,
    const float* __restrict__ q, const float* __restrict__ Wmc,
    const float* __restrict__ cmu, const float* __restrict__ bmu,
    const float* __restrict__ Wlc, const float* __restrict__ cls,
    const float* __restrict__ bls, float* __restrict__ OUT, int N) {
  __shared__ __align__(16) float P[64][68];
  __shared__ __align__(16) float Ws[32][128];
  const int t = threadIdx.x;
  const int r0 = blockIdx.x * 64;
  const int tr = t >> 4;
  const int tc = t & 15;

  gather_tile(rowptr, eidx, Zin, P, r0, N);

  float dv4[4], dq4[4];
#pragma unroll
  for (int i = 0; i < 4; ++i) {
    int r = r0 + tr + 16 * i;
    if (r < N) {
      dv4[i] = dinv[r];
      dq4[i] = dv4[i] * q[r];
    } else {
      dv4[i] = 0.f;
      dq4[i] = 0.f;
    }
  }

  for (int chunk = 0; chunk < 12; ++chunk) {
    const int head = (chunk >= 6) ? 1 : 0;
    const int c0 = (head ? chunk - 6 : chunk) * 128;
    const float* W = head ? Wlc : Wmc;
    const float* cx = head ? cls : cmu;
    const float* b = head ? bls : bmu;
    float* O = OUT + (head ? (size_t)N * 768 : 0);

    float acc[4][8] = {};
    for (int kk = 0; kk < 64; kk += 32) {
      __syncthreads();  // first one also covers P readiness from gather
      for (int i = t; i < 1024; i += 256) {  // 32 k x 128 c as float4s
        int k = i >> 5, c4 = (i & 31) << 2;
        *(float4*)&Ws[k][c4] = *(const float4*)(W + (size_t)(kk + k) * 768 + c0 + c4);
      }
      __syncthreads();
#pragma unroll 4
      for (int k = 0; k < 32; ++k) {
        float4 w0 = *(const float4*)&Ws[k][tc * 4];
        float4 w1 = *(const float4*)&Ws[k][64 + tc * 4];
        float a[4];
        a[0] = P[tr][kk + k];
        a[1] = P[tr + 16][kk + k];
        a[2] = P[tr + 32][kk + k];
        a[3] = P[tr + 48][kk + k];
#pragma unroll
        for (int i = 0; i < 4; ++i) {
          acc[i][0] += a[i] * w0.x;
          acc[i][1] += a[i] * w0.y;
          acc[i][2] += a[i] * w0.z;
          acc[i][3] += a[i] * w0.w;
          acc[i][4] += a[i] * w1.x;
          acc[i][5] += a[i] * w1.y;
          acc[i][6] += a[i] * w1.z;
          acc[i][7] += a[i] * w1.w;
        }
      }
    }

    float4 bb0 = *(const float4*)(b + c0 + tc * 4);
    float4 bb1 = *(const float4*)(b + c0 + 64 + tc * 4);
    float4 cc0 = *(const float4*)(cx + c0 + tc * 4);
    float4 cc1 = *(const float4*)(cx + c0 + 64 + tc * 4);
#pragma unroll
    for (int i = 0; i < 4; ++i) {
      int r = r0 + tr + 16 * i;
      if (r < N) {
        float4 o0 = make_float4(acc[i][0] * dv4[i] + dq4[i] * cc0.x + bb0.x,
                                acc[i][1] * dv4[i] + dq4[i] * cc0.y + bb0.y,
                                acc[i][2] * dv4[i] + dq4[i] * cc0.z + bb0.z,
                                acc[i][3] * dv4[i] + dq4[i] * cc0.w + bb0.w);
        float4 o1 = make_float4(acc[i][4] * dv4[i] + dq4[i] * cc1.x + bb1.x,
                                acc[i][5] * dv4[i] + dq4[i] * cc1.y + bb1.y,
                                acc[i][6] * dv4[i] + dq4[i] * cc1.z + bb1.z,
                                acc[i][7] * dv4[i] + dq4[i] * cc1.w + bb1.w);
        *(float4*)(O + (size_t)r * 768 + c0 + tc * 4) = o0;
        *(float4*)(O + (size_t)r * 768 + c0 + 64 + tc * 4) = o1;
      }
    }
  }
}

extern "C" void kernel_launch(void* const* d_in, const int* in_sizes, int n_in,
                              void* d_out, int out_size, void* d_ws, size_t ws_size,
                              hipStream_t stream) {
  const float* x   = (const float*)d_in[0];
  const int*   ei  = (const int*)d_in[1];
  const float* W1  = (const float*)d_in[2];
  const float* b1  = (const float*)d_in[3];
  const float* g1  = (const float*)d_in[4];
  const float* be1 = (const float*)d_in[5];
  const float* W2  = (const float*)d_in[6];
  const float* b2  = (const float*)d_in[7];
  const float* g2  = (const float*)d_in[8];
  const float* be2 = (const float*)d_in[9];
  const float* W3  = (const float*)d_in[10];
  const float* b3  = (const float*)d_in[11];
  const float* g3  = (const float*)d_in[12];
  const float* be3 = (const float*)d_in[13];
  const float* Wmu = (const float*)d_in[14];
  const float* bmu = (const float*)d_in[15];
  const float* Wls = (const float*)d_in[16];
  const float* bls = (const float*)d_in[17];

  const int N = in_sizes[0] / 3;
  const int E = in_sizes[1] / 2;
  const int* src = ei;
  const int* dst = ei + E;
  float* out = (float*)d_out;

  char* ws = (char*)d_ws;
  size_t o = 0;
  float* dinv = (float*)(ws + o); o += (size_t)N * 4;
  float* qv   = (float*)(ws + o); o += (size_t)N * 4;
  float* bns  = (float*)(ws + o); o += 384 * 4;
  float* W2c  = (float*)(ws + o); o += 4096 * 4;
  float* c2   = (float*)(ws + o); o += 64 * 4;
  float* W3c  = (float*)(ws + o); o += 4096 * 4;
  float* c3   = (float*)(ws + o); o += 64 * 4;
  float* Wmc  = (float*)(ws + o); o += (size_t)64 * 768 * 4;
  float* cmu  = (float*)(ws + o); o += 768 * 4;
  float* Wlc  = (float*)(ws + o); o += (size_t)64 * 768 * 4;
  float* cls  = (float*)(ws + o); o += 768 * 4;
  int* cnt    = (int*)(ws + o);   o += (size_t)N * 4;
  int* rowptr = (int*)(ws + o);   o += ((size_t)N + 1) * 4;
  int* cursor = (int*)(ws + o);   o += (size_t)N * 4;
  int* bsum   = (int*)(ws + o);   o += 64 * 4;
  int* eidx   = (int*)(ws + o);   o += (size_t)E * 4;
  float* B0   = (float*)(ws + o); o += (size_t)N * 64 * 4;
  float* B1   = (float*)(ws + o); o += (size_t)N * 64 * 4;
  // ws_size observed ~1.2 GB; total used ~31 MB.

  const float invN = 1.0f / (float)N;
  int nbN = (N + 255) / 256;
  int nbE = (E + 255) / 256;
  int gb  = (N + 63) / 64;
  int sbA = (N + 1023) / 1024;

  // CSR build (edge_index constant across all 4 propagations)
  init_k<<<nbN, 256, 0, stream>>>(cnt, bns, N);
  hist_k<<<nbE, 256, 0, stream>>>(dst, cnt, E);
  scanA<<<sbA, 1024, 0, stream>>>(cnt, rowptr, bsum, N);
  scanB<<<1, 64, 0, stream>>>(bsum, sbA);
  scanC<<<nbN, 256, 0, stream>>>(cnt, rowptr, cursor, bsum, dinv, N, E);
  fill_k<<<nbE, 256, 0, stream>>>(src, dst, cursor, eidx, E);

  // ---- layer 1: fused gather(3ch)+GEMM+stats, writes Z1=B0 and q ----
  l1_fused<<<1024, 256, 0, stream>>>(rowptr, eidx, x, dinv, W1, b1, B0, qv, bns, N);
  prep_small<<<1, 256, 0, stream>>>(bns + 0, g1, be1, W2, W2c, c2, invN);

  // ---- layer 2: gather(B0) fused into GEMM, writes Z2=B1 ----
  gemm_bnq_f<<<gb, 256, 0, stream>>>(rowptr, eidx, B0, dinv, qv, W2c, c2, b2,
                                     B1, bns + 128, N);
  prep_small<<<1, 256, 0, stream>>>(bns + 128, g2, be2, W3, W3c, c3, invN);

  // ---- layer 3: gather(B1) fused into GEMM, writes Z3=B0 ----
  gemm_bnq_f<<<gb, 256, 0, stream>>>(rowptr, eidx, B1, dinv, qv, W3c, c3, b3,
                                     B0, bns + 256, N);
  prep_head<<<12, 256, 0, stream>>>(bns + 256, g3, be3, Wmu, Wls, Wmc, Wlc, cmu, cls, invN);

  // ---- heads: gather(B0) fused, all 768+768 cols per row-block ----
  head_f<<<gb, 256, 0, stream>>>(rowptr, eidx, B0, dinv, qv, Wmc, cmu, bmu,
                                 Wlc, cls, bls, out, N);
}

// Round 11
// 454.590 us; speedup vs baseline: 1.0779x; 1.0779x over previous
//
#include <hip/hip_runtime.h>
#include <cstddef>

// GCN encoder, BN-folded formulation.
// prop(h)[d] = dinv[d]*(P(h)[d] @ W) + b, P(h)[d] = sum_{s in N(d)+self} dinv[s]*h[s].
// BN(z) = z*sc + sh  =>  P(BN(o))[d] = sc (.) P(o)[d] + q[d]*sh, q graph-only.
// Layers 2/3 gather their 64-row tile in-block (gemm_bnq_f). The head keeps a
// SPLIT gather64 -> head_gemm2: fusing them (r10) lost 55us because the fused
// kernel's 782 blocks serialize {latency-bound gather}->{compute} with no
// cross-block phase overlap, while split gather64 (12.5k blocks) and
// head_gemm2 (9.4k blocks) each saturate their own regime.

#define NEG_SLOPE 0.01f
#define BN_EPS 1e-5f

__global__ __launch_bounds__(256) void init_k(int* __restrict__ cnt,
                                              float* __restrict__ bns, int N) {
  int i = blockIdx.x * 256 + threadIdx.x;
  if (i < N) cnt[i] = 0;
  if (i < 384) bns[i] = 0.0f;  // 3 layers x {sum[64], sumsq[64]}
}

__global__ __launch_bounds__(256) void hist_k(const int* __restrict__ dst,
                                              int* __restrict__ cnt, int E) {
  int e = blockIdx.x * 256 + threadIdx.x;
  if (e < E) atomicAdd(&cnt[dst[e]], 1);
}

// Multi-block scan, phase A: block-local exclusive scan of cnt into pre
// (=rowptr used as scratch), block totals into bsum.
__global__ __launch_bounds__(1024) void scanA(const int* __restrict__ cnt,
                                              int* __restrict__ pre,
                                              int* __restrict__ bsum, int N) {
  __shared__ int sh[1024];
  const int t = threadIdx.x;
  const int i = blockIdx.x * 1024 + t;
  int c = (i < N) ? cnt[i] : 0;
  sh[t] = c;
  __syncthreads();
  for (int off = 1; off < 1024; off <<= 1) {
    int v = (t >= off) ? sh[t - off] : 0;
    __syncthreads();
    sh[t] += v;
    __syncthreads();
  }
  if (i < N) pre[i] = sh[t] - c;  // exclusive
  if (t == 1023) bsum[blockIdx.x] = sh[t];
}

// Phase B: single-wave exclusive scan of nb (<=64) block sums in place.
__global__ __launch_bounds__(64) void scanB(int* __restrict__ bsum, int nb) {
  int t = threadIdx.x;
  int orig = (t < nb) ? bsum[t] : 0;
  int v = orig;
#pragma unroll
  for (int off = 1; off < 64; off <<= 1) {
    int u = __shfl_up(v, off);
    if (t >= off) v += u;
  }
  if (t < nb) bsum[t] = v - orig;
}

// Phase C: rowptr = pre + bsum[blk]; cursor copy; dinv = rsqrt(deg+1).
__global__ __launch_bounds__(256) void scanC(const int* __restrict__ cnt,
                                             int* __restrict__ rowptr,
                                             int* __restrict__ cursor,
                                             const int* __restrict__ bsum,
                                             float* __restrict__ dinv,
                                             int N, int E) {
  int i = blockIdx.x * 256 + threadIdx.x;
  if (i < N) {
    int rp = rowptr[i] + bsum[i >> 10];
    rowptr[i] = rp;
    cursor[i] = rp;
    dinv[i] = rsqrtf((float)(cnt[i] + 1));  // +1 self loop
  }
  if (i == 0) rowptr[N] = E;
}

__global__ __launch_bounds__(256) void fill_k(const int* __restrict__ src,
                                              const int* __restrict__ dst,
                                              int* __restrict__ cursor,
                                              int* __restrict__ eidx, int E) {
  int e = blockIdx.x * 256 + threadIdx.x;
  if (e >= E) return;
  int p = atomicAdd(&cursor[dst[e]], 1);
  eidx[p] = src[e];
}

// Layer 1 fully fused: per node (one wave, grid-stride):
//   agg(3ch) = x[node]*dv + sum_e x[src]*dinv[src];  q[node] = dv + sum dinv[src]
//   u = dv*(agg @ W1) + b1; o = LeakyReLU(u); Z1 = o*dv; BN stats of o.
__global__ __launch_bounds__(256) void l1_fused(
    const int* __restrict__ rowptr, const int* __restrict__ eidx,
    const float* __restrict__ x, const float* __restrict__ dinv,
    const float* __restrict__ W1, const float* __restrict__ b1,
    float* __restrict__ Z, float* __restrict__ q, float* __restrict__ bns, int N) {
  const int t = threadIdx.x, lane = t & 63, wid = t >> 6;
  const int gw = blockIdx.x * 4 + wid;
  const int nw = gridDim.x * 4;
  const float w0 = W1[lane], w1 = W1[64 + lane], w2 = W1[128 + lane];
  const float bb = b1[lane];
  float s1 = 0.f, s2 = 0.f;
  for (int node = gw; node < N; node += nw) {
    int beg = rowptr[node], end = rowptr[node + 1];
    float a0 = 0.f, a1 = 0.f, a2 = 0.f, aq = 0.f;
    for (int e = beg + lane; e < end; e += 64) {
      int s = eidx[e];
      float dv = dinv[s];
      a0 += x[s * 3] * dv;
      a1 += x[s * 3 + 1] * dv;
      a2 += x[s * 3 + 2] * dv;
      aq += dv;
    }
#pragma unroll
    for (int off = 32; off; off >>= 1) {
      a0 += __shfl_xor(a0, off);
      a1 += __shfl_xor(a1, off);
      a2 += __shfl_xor(a2, off);
      aq += __shfl_xor(aq, off);
    }
    float dv = dinv[node];
    a0 += x[node * 3] * dv;
    a1 += x[node * 3 + 1] * dv;
    a2 += x[node * 3 + 2] * dv;
    aq += dv;
    float u = dv * (a0 * w0 + a1 * w1 + a2 * w2) + bb;
    float o = u >= 0.f ? u : NEG_SLOPE * u;
    Z[(size_t)node * 64 + lane] = o * dv;
    s1 += o;
    s2 += o * o;
    if (lane == 0) q[node] = aq;
  }
  __shared__ float red[8][64];
  red[wid][lane] = s1;
  red[4 + wid][lane] = s2;
  __syncthreads();
  if (t < 64) {
    atomicAdd(&bns[t], red[0][t] + red[1][t] + red[2][t] + red[3][t]);
    atomicAdd(&bns[64 + t], red[4][t] + red[5][t] + red[6][t] + red[7][t]);
  }
}

// Standalone gather (final propagate): G[node][c] = Z[node][c] + sum Z[src][c].
// One wave per node; lane = (slot: lane>>4) x (4 ch: (lane&15)*4); 4 edges/iter
// unroll 2 -> 8 edges in flight (16B/lane float4); shfl_xor(16|32) reduce.
__global__ __launch_bounds__(256) void gather64(const int* __restrict__ rowptr,
                                                const int* __restrict__ eidx,
                                                const float* __restrict__ Z,
                                                float* __restrict__ G, int N) {
  int node = blockIdx.x * 4 + (threadIdx.x >> 6);
  if (node >= N) return;
  int lane = threadIdx.x & 63;
  int slot = lane >> 4;
  int c4 = (lane & 15) << 2;
  int beg = rowptr[node], end = rowptr[node + 1];
  float ax = 0.f, ay = 0.f, az = 0.f, aw = 0.f;
  int e = beg + slot;
  for (; e + 4 < end; e += 8) {
    int s0 = eidx[e], s1 = eidx[e + 4];
    float4 v0 = *(const float4*)(Z + (size_t)s0 * 64 + c4);
    float4 v1 = *(const float4*)(Z + (size_t)s1 * 64 + c4);
    ax += v0.x + v1.x;
    ay += v0.y + v1.y;
    az += v0.z + v1.z;
    aw += v0.w + v1.w;
  }
  if (e < end) {
    int s0 = eidx[e];
    float4 v0 = *(const float4*)(Z + (size_t)s0 * 64 + c4);
    ax += v0.x; ay += v0.y; az += v0.z; aw += v0.w;
  }
#pragma unroll
  for (int off = 16; off < 64; off <<= 1) {
    ax += __shfl_xor(ax, off);
    ay += __shfl_xor(ay, off);
    az += __shfl_xor(az, off);
    aw += __shfl_xor(aw, off);
  }
  if (slot == 0) {
    float4 self = *(const float4*)(Z + (size_t)node * 64 + c4);
    float4 o = make_float4(ax + self.x, ay + self.y, az + self.z, aw + self.w);
    *(float4*)(G + (size_t)node * 64 + c4) = o;
  }
}

// In-block CSR gather of a 64-row tile into LDS P (used by layers 2/3).
__device__ __forceinline__ void gather_tile(
    const int* __restrict__ rowptr, const int* __restrict__ eidx,
    const float* __restrict__ Z, float (*__restrict__ P)[68], int r0, int N) {
  const int t = threadIdx.x;
  const int lane = t & 63, wid = t >> 6;
  const int slot = lane >> 4, c4 = (lane & 15) << 2;
#pragma unroll 1
  for (int i = 0; i < 16; ++i) {
    const int r = wid * 16 + i;
    const int gr = r0 + r;
    float ax = 0.f, ay = 0.f, az = 0.f, aw = 0.f;
    if (gr < N) {
      const int beg = rowptr[gr], end = rowptr[gr + 1];
      int e = beg + slot;
      for (; e + 4 < end; e += 8) {
        int s0 = eidx[e], s1 = eidx[e + 4];
        float4 v0 = *(const float4*)(Z + (size_t)s0 * 64 + c4);
        float4 v1 = *(const float4*)(Z + (size_t)s1 * 64 + c4);
        ax += v0.x + v1.x;
        ay += v0.y + v1.y;
        az += v0.z + v1.z;
        aw += v0.w + v1.w;
      }
      if (e < end) {
        int s0 = eidx[e];
        float4 v0 = *(const float4*)(Z + (size_t)s0 * 64 + c4);
        ax += v0.x; ay += v0.y; az += v0.z; aw += v0.w;
      }
    }
#pragma unroll
    for (int off = 16; off < 64; off <<= 1) {
      ax += __shfl_xor(ax, off);
      ay += __shfl_xor(ay, off);
      az += __shfl_xor(az, off);
      aw += __shfl_xor(aw, off);
    }
    if (slot == 0) {
      float4 o = make_float4(0.f, 0.f, 0.f, 0.f);
      if (gr < N) {
        float4 self = *(const float4*)(Z + (size_t)gr * 64 + c4);
        o = make_float4(ax + self.x, ay + self.y, az + self.z, aw + self.w);
      }
      *(float4*)&P[r][c4] = o;
    }
  }
}

// sc/sh from bns, then W'[k][c] = sc[k]*W[k][c] (64x64), c'[c] = sum_k sh[k]*W[k][c].
__global__ __launch_bounds__(256) void prep_small(
    const float* __restrict__ bns, const float* __restrict__ g,
    const float* __restrict__ be, const float* __restrict__ W,
    float* __restrict__ Wc, float* __restrict__ cx, float invN) {
  __shared__ float sc[64], sh[64], part[4][64];
  int t = threadIdx.x;
  if (t < 64) {
    float mean = bns[t] * invN;
    float var = bns[64 + t] * invN - mean * mean;
    float s = g[t] * rsqrtf(var + BN_EPS);
    sc[t] = s;
    sh[t] = be[t] - mean * s;
  }
  __syncthreads();
  int c = t & 63, kq = t >> 6;
  float p = 0.f;
  for (int k = kq * 16; k < kq * 16 + 16; ++k) {
    float w = W[k * 64 + c];
    Wc[k * 64 + c] = sc[k] * w;
    p += sh[k] * w;
  }
  part[kq][c] = p;
  __syncthreads();
  if (t < 64) cx[t] = part[0][t] + part[1][t] + part[2][t] + part[3][t];
}

// Same for the two 64x768 head weights. grid.x = 12: 0-5 mu, 6-11 ls (128 cols each).
__global__ __launch_bounds__(256) void prep_head(
    const float* __restrict__ bns, const float* __restrict__ g,
    const float* __restrict__ be, const float* __restrict__ Wmu,
    const float* __restrict__ Wls, float* __restrict__ Wmc,
    float* __restrict__ Wlc, float* __restrict__ cmu, float* __restrict__ cls,
    float invN) {
  __shared__ float sc[64], sh[64], part[2][128];
  int t = threadIdx.x;
  if (t < 64) {
    float mean = bns[t] * invN;
    float var = bns[64 + t] * invN - mean * mean;
    float s = g[t] * rsqrtf(var + BN_EPS);
    sc[t] = s;
    sh[t] = be[t] - mean * s;
  }
  __syncthreads();
  int blk = blockIdx.x;
  int head = blk >= 6 ? 1 : 0;
  int c0 = (head ? blk - 6 : blk) * 128;
  const float* W = head ? Wls : Wmu;
  float* Wc = head ? Wlc : Wmc;
  float* cx = head ? cls : cmu;
  int c = c0 + (t & 127), kh = t >> 7;
  float p = 0.f;
  for (int k = kh * 32; k < kh * 32 + 32; ++k) {
    float w = W[(size_t)k * 768 + c];
    Wc[(size_t)k * 768 + c] = sc[k] * w;
    p += sh[k] * w;
  }
  part[kh][t & 127] = p;
  __syncthreads();
  if (t < 128) cx[c0 + t] = part[0][t] + part[1][t];
}

// Layers 2/3: gather tile in-block, then
// Z_next = LeakyReLU(dv*(P @ Wc) + dv*q[r]*cx + b) * dv, plus BN stats of o.
__global__ __launch_bounds__(256, 4) void gemm_bnq_f(
    const int* __restrict__ rowptr, const int* __restrict__ eidx,
    const float* __restrict__ Zin, const float* __restrict__ dinv,
    const float* __restrict__ q, const float* __restrict__ Wc,
    const float* __restrict__ cx, const float* __restrict__ b,
    float* __restrict__ Z, float* __restrict__ bns, int N) {
  __shared__ __align__(16) float P[64][68];
  __shared__ __align__(16) float Ws[64][64];
  const int t = threadIdx.x;
  const int r0 = blockIdx.x * 64;

  for (int i = t; i < 4096; i += 256) Ws[i >> 6][i & 63] = Wc[i];
  gather_tile(rowptr, eidx, Zin, P, r0, N);
  __syncthreads();

  const int tr = t >> 4, tc4 = (t & 15) << 2;
  float acc[4][4] = {};
#pragma unroll 8
  for (int k = 0; k < 64; ++k) {
    float4 w = *(const float4*)&Ws[k][tc4];
#pragma unroll
    for (int i = 0; i < 4; ++i) {
      float a = P[tr + 16 * i][k];
      acc[i][0] += a * w.x;
      acc[i][1] += a * w.y;
      acc[i][2] += a * w.z;
      acc[i][3] += a * w.w;
    }
  }

  float s1[4] = {0.f, 0.f, 0.f, 0.f}, s2[4] = {0.f, 0.f, 0.f, 0.f};
  float4 bb = *(const float4*)(b + tc4);
  float4 cc = *(const float4*)(cx + tc4);
#pragma unroll
  for (int i = 0; i < 4; ++i) {
    int r = r0 + tr + 16 * i;
    if (r < N) {
      float dv = dinv[r];
      float dq = dv * q[r];
      float u0 = acc[i][0] * dv + dq * cc.x + bb.x;
      float u1 = acc[i][1] * dv + dq * cc.y + bb.y;
      float u2 = acc[i][2] * dv + dq * cc.z + bb.z;
      float u3 = acc[i][3] * dv + dq * cc.w + bb.w;
      float o0 = u0 >= 0.f ? u0 : NEG_SLOPE * u0;
      float o1 = u1 >= 0.f ? u1 : NEG_SLOPE * u1;
      float o2 = u2 >= 0.f ? u2 : NEG_SLOPE * u2;
      float o3 = u3 >= 0.f ? u3 : NEG_SLOPE * u3;
      float4 z = make_float4(o0 * dv, o1 * dv, o2 * dv, o3 * dv);
      *(float4*)(Z + (size_t)r * 64 + tc4) = z;
      s1[0] += o0; s2[0] += o0 * o0;
      s1[1] += o1; s2[1] += o1 * o1;
      s1[2] += o2; s2[2] += o2 * o2;
      s1[3] += o3; s2[3] += o3 * o3;
    }
  }
  __syncthreads();  // Ws no longer needed; reuse for BN reduction
  float (*red1)[64] = (float(*)[64]) & Ws[0][0];
  float (*red2)[64] = (float(*)[64]) & Ws[16][0];
#pragma unroll
  for (int j = 0; j < 4; ++j) {
    red1[tr][tc4 + j] = s1[j];
    red2[tr][tc4 + j] = s2[j];
  }
  __syncthreads();
  if (t < 64) {
    float a1 = 0.f, a2 = 0.f;
#pragma unroll
    for (int i = 0; i < 16; ++i) {
      a1 += red1[i][t];
      a2 += red2[i][t];
    }
    atomicAdd(&bns[t], a1);
    atomicAdd(&bns[64 + t], a2);
  }
}

// Both heads. 64 rows x 128 cols per block; grid y: 0-5 mu, 6-11 ls.
// out = dv*(G @ Wc) + dv*q[r]*cx + b.
__global__ __launch_bounds__(256, 4) void head_gemm2(
    const float* __restrict__ G, const float* __restrict__ dinv,
    const float* __restrict__ q, const float* __restrict__ Wmc,
    const float* __restrict__ cmu, const float* __restrict__ bmu,
    const float* __restrict__ Wlc, const float* __restrict__ cls,
    const float* __restrict__ bls, float* __restrict__ OUT, int N) {
  __shared__ __align__(16) float P[64][68];
  __shared__ __align__(16) float Ws[32][128];
  const int t = threadIdx.x;
  const int r0 = blockIdx.x * 64;
  const int yy = blockIdx.y;
  const int head = (yy >= 6) ? 1 : 0;
  const int c0 = (head ? yy - 6 : yy) * 128;
  const float* W = head ? Wlc : Wmc;
  const float* cx = head ? cls : cmu;
  const float* b = head ? bls : bmu;
  float* O = OUT + (head ? (size_t)N * 768 : 0);

  for (int i = t; i < 1024; i += 256) {
    int r = i >> 4, k4 = (i & 15) << 2, gr = r0 + r;
    float4 v = make_float4(0.f, 0.f, 0.f, 0.f);
    if (gr < N) v = *(const float4*)(G + (size_t)gr * 64 + k4);
    *(float4*)&P[r][k4] = v;
  }

  const int tr = t >> 4;
  const int tc = t & 15;
  float acc[4][8] = {};

  for (int kk = 0; kk < 64; kk += 32) {
    __syncthreads();
    for (int i = t; i < 1024; i += 256) {
      int k = i >> 5, c4 = (i & 31) << 2;
      *(float4*)&Ws[k][c4] = *(const float4*)(W + (size_t)(kk + k) * 768 + c0 + c4);
    }
    __syncthreads();
#pragma unroll 4
    for (int k = 0; k < 32; ++k) {
      float4 w0 = *(const float4*)&Ws[k][tc * 4];
      float4 w1 = *(const float4*)&Ws[k][64 + tc * 4];
      float a[4];
      a[0] = P[tr][kk + k];
      a[1] = P[tr + 16][kk + k];
      a[2] = P[tr + 32][kk + k];
      a[3] = P[tr + 48][kk + k];
#pragma unroll
      for (int i = 0; i < 4; ++i) {
        acc[i][0] += a[i] * w0.x;
        acc[i][1] += a[i] * w0.y;
        acc[i][2] += a[i] * w0.z;
        acc[i][3] += a[i] * w0.w;
        acc[i][4] += a[i] * w1.x;
        acc[i][5] += a[i] * w1.y;
        acc[i][6] += a[i] * w1.z;
        acc[i][7] += a[i] * w1.w;
      }
    }
  }

  float4 bb0 = *(const float4*)(b + c0 + tc * 4);
  float4 bb1 = *(const float4*)(b + c0 + 64 + tc * 4);
  float4 cc0 = *(const float4*)(cx + c0 + tc * 4);
  float4 cc1 = *(const float4*)(cx + c0 + 64 + tc * 4);
#pragma unroll
  for (int i = 0; i < 4; ++i) {
    int r = r0 + tr + 16 * i;
    if (r < N) {
      float dv = dinv[r];
      float dq = dv * q[r];
      float4 o0 = make_float4(acc[i][0] * dv + dq * cc0.x + bb0.x,
                              acc[i][1] * dv + dq * cc0.y + bb0.y,
                              acc[i][2] * dv + dq * cc0.z + bb0.z,
                              acc[i][3] * dv + dq * cc0.w + bb0.w);
      float4 o1 = make_float4(acc[i][4] * dv + dq * cc1.x + bb1.x,
                              acc[i][5] * dv + dq * cc1.y + bb1.y,
                              acc[i][6] * dv + dq * cc1.z + bb1.z,
                              acc[i][7] * dv + dq * cc1.w + bb1.w);
      *(float4*)(O + (size_t)r * 768 + c0 + tc * 4) = o0;
      *(float4*)(O + (size_t)r * 768 + c0 + 64 + tc * 4) = o1;
    }
  }
}

extern "C" void kernel_launch(void* const* d_in, const int* in_sizes, int n_in,
                              void* d_out, int out_size, void* d_ws, size_t ws_size,
                              hipStream_t stream) {
  const float* x   = (const float*)d_in[0];
  const int*   ei  = (const int*)d_in[1];
  const float* W1  = (const float*)d_in[2];
  const float* b1  = (const float*)d_in[3];
  const float* g1  = (const float*)d_in[4];
  const float* be1 = (const float*)d_in[5];
  const float* W2  = (const float*)d_in[6];
  const float* b2  = (const float*)d_in[7];
  const float* g2  = (const float*)d_in[8];
  const float* be2 = (const float*)d_in[9];
  const float* W3  = (const float*)d_in[10];
  const float* b3  = (const float*)d_in[11];
  const float* g3  = (const float*)d_in[12];
  const float* be3 = (const float*)d_in[13];
  const float* Wmu = (const float*)d_in[14];
  const float* bmu = (const float*)d_in[15];
  const float* Wls = (const float*)d_in[16];
  const float* bls = (const float*)d_in[17];

  const int N = in_sizes[0] / 3;
  const int E = in_sizes[1] / 2;
  const int* src = ei;
  const int* dst = ei + E;
  float* out = (float*)d_out;

  char* ws = (char*)d_ws;
  size_t o = 0;
  float* dinv = (float*)(ws + o); o += (size_t)N * 4;
  float* qv   = (float*)(ws + o); o += (size_t)N * 4;
  float* bns  = (float*)(ws + o); o += 384 * 4;
  float* W2c  = (float*)(ws + o); o += 4096 * 4;
  float* c2   = (float*)(ws + o); o += 64 * 4;
  float* W3c  = (float*)(ws + o); o += 4096 * 4;
  float* c3   = (float*)(ws + o); o += 64 * 4;
  float* Wmc  = (float*)(ws + o); o += (size_t)64 * 768 * 4;
  float* cmu  = (float*)(ws + o); o += 768 * 4;
  float* Wlc  = (float*)(ws + o); o += (size_t)64 * 768 * 4;
  float* cls  = (float*)(ws + o); o += 768 * 4;
  int* cnt    = (int*)(ws + o);   o += (size_t)N * 4;
  int* rowptr = (int*)(ws + o);   o += ((size_t)N + 1) * 4;
  int* cursor = (int*)(ws + o);   o += (size_t)N * 4;
  int* bsum   = (int*)(ws + o);   o += 64 * 4;
  int* eidx   = (int*)(ws + o);   o += (size_t)E * 4;
  float* B0   = (float*)(ws + o); o += (size_t)N * 64 * 4;
  float* B1   = (float*)(ws + o); o += (size_t)N * 64 * 4;
  // ws_size observed ~1.2 GB; total used ~31 MB.

  const float invN = 1.0f / (float)N;
  int nbN = (N + 255) / 256;
  int nbE = (E + 255) / 256;
  int gb  = (N + 63) / 64;
  int wb  = (N + 3) / 4;
  int sbA = (N + 1023) / 1024;

  // CSR build (edge_index constant across all 4 propagations)
  init_k<<<nbN, 256, 0, stream>>>(cnt, bns, N);
  hist_k<<<nbE, 256, 0, stream>>>(dst, cnt, E);
  scanA<<<sbA, 1024, 0, stream>>>(cnt, rowptr, bsum, N);
  scanB<<<1, 64, 0, stream>>>(bsum, sbA);
  scanC<<<nbN, 256, 0, stream>>>(cnt, rowptr, cursor, bsum, dinv, N, E);
  fill_k<<<nbE, 256, 0, stream>>>(src, dst, cursor, eidx, E);

  // ---- layer 1: fused gather(3ch)+GEMM+stats, writes Z1=B0 and q ----
  l1_fused<<<1024, 256, 0, stream>>>(rowptr, eidx, x, dinv, W1, b1, B0, qv, bns, N);
  prep_small<<<1, 256, 0, stream>>>(bns + 0, g1, be1, W2, W2c, c2, invN);

  // ---- layer 2: gather(B0) fused into GEMM, writes Z2=B1 ----
  gemm_bnq_f<<<gb, 256, 0, stream>>>(rowptr, eidx, B0, dinv, qv, W2c, c2, b2,
                                     B1, bns + 128, N);
  prep_small<<<1, 256, 0, stream>>>(bns + 128, g2, be2, W3, W3c, c3, invN);

  // ---- layer 3: gather(B1) fused into GEMM, writes Z3=B0 ----
  gemm_bnq_f<<<gb, 256, 0, stream>>>(rowptr, eidx, B1, dinv, qv, W3c, c3, b3,
                                     B0, bns + 256, N);
  prep_head<<<12, 256, 0, stream>>>(bns + 256, g3, be3, Wmu, Wls, Wmc, Wlc, cmu, cls, invN);

  // ---- final propagate (standalone, max parallelism) + split head GEMM ----
  gather64<<<wb, 256, 0, stream>>>(rowptr, eidx, B0, B1, N);      // B1 = G3
  dim3 hgrid(gb, 12);
  head_gemm2<<<hgrid, 256, 0, stream>>>(B1, dinv, qv, Wmc, cmu, bmu, Wlc, cls, bls, out, N);
}

// Round 12
// 440.888 us; speedup vs baseline: 1.1114x; 1.0311x over previous
//
#include <hip/hip_runtime.h>
#include <cstddef>

// GCN encoder, BN-folded formulation. SPLIT gather->GEMM everywhere:
// in-block gather fusion measured net-negative (r10 head: +55us, r11 layers:
// +10us) — the fused blocks serialize {latency-gather}->{compute} with no
// cross-block phase overlap. Head GEMM uses 128x128 tiles (r12).
// prop(h)[d] = dinv[d]*(P(h)[d] @ W) + b, P(h)[d] = sum_{s in N(d)+self} dinv[s]*h[s].
// BN(z) = z*sc + sh  =>  P(BN(o))[d] = sc (.) P(o)[d] + q[d]*sh, q graph-only.
// Each GEMM consumes G = gather(Z), Z = o*dinv, with W' = diag(sc)@W,
// c' = sh@W, epilogue u = dv*acc + dv*q[r]*c'[c] + b[c]. BN stats in epilogue.

#define NEG_SLOPE 0.01f
#define BN_EPS 1e-5f

__global__ __launch_bounds__(256) void init_k(int* __restrict__ cnt,
                                              float* __restrict__ bns, int N) {
  int i = blockIdx.x * 256 + threadIdx.x;
  if (i < N) cnt[i] = 0;
  if (i < 384) bns[i] = 0.0f;  // 3 layers x {sum[64], sumsq[64]}
}

__global__ __launch_bounds__(256) void hist_k(const int* __restrict__ dst,
                                              int* __restrict__ cnt, int E) {
  int e = blockIdx.x * 256 + threadIdx.x;
  if (e < E) atomicAdd(&cnt[dst[e]], 1);
}

// Multi-block scan, phase A: block-local exclusive scan of cnt into pre
// (=rowptr used as scratch), block totals into bsum.
__global__ __launch_bounds__(1024) void scanA(const int* __restrict__ cnt,
                                              int* __restrict__ pre,
                                              int* __restrict__ bsum, int N) {
  __shared__ int sh[1024];
  const int t = threadIdx.x;
  const int i = blockIdx.x * 1024 + t;
  int c = (i < N) ? cnt[i] : 0;
  sh[t] = c;
  __syncthreads();
  for (int off = 1; off < 1024; off <<= 1) {
    int v = (t >= off) ? sh[t - off] : 0;
    __syncthreads();
    sh[t] += v;
    __syncthreads();
  }
  if (i < N) pre[i] = sh[t] - c;  // exclusive
  if (t == 1023) bsum[blockIdx.x] = sh[t];
}

// Phase B: single-wave exclusive scan of nb (<=64) block sums in place.
__global__ __launch_bounds__(64) void scanB(int* __restrict__ bsum, int nb) {
  int t = threadIdx.x;
  int orig = (t < nb) ? bsum[t] : 0;
  int v = orig;
#pragma unroll
  for (int off = 1; off < 64; off <<= 1) {
    int u = __shfl_up(v, off);
    if (t >= off) v += u;
  }
  if (t < nb) bsum[t] = v - orig;
}

// Phase C: rowptr = pre + bsum[blk]; cursor copy; dinv = rsqrt(deg+1).
__global__ __launch_bounds__(256) void scanC(const int* __restrict__ cnt,
                                             int* __restrict__ rowptr,
                                             int* __restrict__ cursor,
                                             const int* __restrict__ bsum,
                                             float* __restrict__ dinv,
                                             int N, int E) {
  int i = blockIdx.x * 256 + threadIdx.x;
  if (i < N) {
    int rp = rowptr[i] + bsum[i >> 10];
    rowptr[i] = rp;
    cursor[i] = rp;
    dinv[i] = rsqrtf((float)(cnt[i] + 1));  // +1 self loop
  }
  if (i == 0) rowptr[N] = E;
}

__global__ __launch_bounds__(256) void fill_k(const int* __restrict__ src,
                                              const int* __restrict__ dst,
                                              int* __restrict__ cursor,
                                              int* __restrict__ eidx, int E) {
  int e = blockIdx.x * 256 + threadIdx.x;
  if (e >= E) return;
  int p = atomicAdd(&cursor[dst[e]], 1);
  eidx[p] = src[e];
}

// Layer 1 fully fused: per node (one wave, grid-stride):
//   agg(3ch) = x[node]*dv + sum_e x[src]*dinv[src];  q[node] = dv + sum dinv[src]
//   u = dv*(agg @ W1) + b1; o = LeakyReLU(u); Z1 = o*dv; BN stats of o.
__global__ __launch_bounds__(256) void l1_fused(
    const int* __restrict__ rowptr, const int* __restrict__ eidx,
    const float* __restrict__ x, const float* __restrict__ dinv,
    const float* __restrict__ W1, const float* __restrict__ b1,
    float* __restrict__ Z, float* __restrict__ q, float* __restrict__ bns, int N) {
  const int t = threadIdx.x, lane = t & 63, wid = t >> 6;
  const int gw = blockIdx.x * 4 + wid;
  const int nw = gridDim.x * 4;
  const float w0 = W1[lane], w1 = W1[64 + lane], w2 = W1[128 + lane];
  const float bb = b1[lane];
  float s1 = 0.f, s2 = 0.f;
  for (int node = gw; node < N; node += nw) {
    int beg = rowptr[node], end = rowptr[node + 1];
    float a0 = 0.f, a1 = 0.f, a2 = 0.f, aq = 0.f;
    for (int e = beg + lane; e < end; e += 64) {
      int s = eidx[e];
      float dv = dinv[s];
      a0 += x[s * 3] * dv;
      a1 += x[s * 3 + 1] * dv;
      a2 += x[s * 3 + 2] * dv;
      aq += dv;
    }
#pragma unroll
    for (int off = 32; off; off >>= 1) {
      a0 += __shfl_xor(a0, off);
      a1 += __shfl_xor(a1, off);
      a2 += __shfl_xor(a2, off);
      aq += __shfl_xor(aq, off);
    }
    float dv = dinv[node];
    a0 += x[node * 3] * dv;
    a1 += x[node * 3 + 1] * dv;
    a2 += x[node * 3 + 2] * dv;
    aq += dv;
    float u = dv * (a0 * w0 + a1 * w1 + a2 * w2) + bb;
    float o = u >= 0.f ? u : NEG_SLOPE * u;
    Z[(size_t)node * 64 + lane] = o * dv;
    s1 += o;
    s2 += o * o;
    if (lane == 0) q[node] = aq;
  }
  __shared__ float red[8][64];
  red[wid][lane] = s1;
  red[4 + wid][lane] = s2;
  __syncthreads();
  if (t < 64) {
    atomicAdd(&bns[t], red[0][t] + red[1][t] + red[2][t] + red[3][t]);
    atomicAdd(&bns[64 + t], red[4][t] + red[5][t] + red[6][t] + red[7][t]);
  }
}

// Standalone gather: G[node][c] = Z[node][c] + sum Z[src][c]; one wave/node.
// lane = (slot: lane>>4) x (4 ch: (lane&15)*4); 4 edges/iter, unroll 2 ->
// 8 edges in flight (16B/lane float4); shfl_xor(16|32) cross-slot reduce.
__global__ __launch_bounds__(256) void gather64(const int* __restrict__ rowptr,
                                                const int* __restrict__ eidx,
                                                const float* __restrict__ Z,
                                                float* __restrict__ G, int N) {
  int node = blockIdx.x * 4 + (threadIdx.x >> 6);
  if (node >= N) return;
  int lane = threadIdx.x & 63;
  int slot = lane >> 4;
  int c4 = (lane & 15) << 2;
  int beg = rowptr[node], end = rowptr[node + 1];
  float ax = 0.f, ay = 0.f, az = 0.f, aw = 0.f;
  int e = beg + slot;
  for (; e + 4 < end; e += 8) {
    int s0 = eidx[e], s1 = eidx[e + 4];
    float4 v0 = *(const float4*)(Z + (size_t)s0 * 64 + c4);
    float4 v1 = *(const float4*)(Z + (size_t)s1 * 64 + c4);
    ax += v0.x + v1.x;
    ay += v0.y + v1.y;
    az += v0.z + v1.z;
    aw += v0.w + v1.w;
  }
  if (e < end) {
    int s0 = eidx[e];
    float4 v0 = *(const float4*)(Z + (size_t)s0 * 64 + c4);
    ax += v0.x; ay += v0.y; az += v0.z; aw += v0.w;
  }
#pragma unroll
  for (int off = 16; off < 64; off <<= 1) {
    ax += __shfl_xor(ax, off);
    ay += __shfl_xor(ay, off);
    az += __shfl_xor(az, off);
    aw += __shfl_xor(aw, off);
  }
  if (slot == 0) {
    float4 self = *(const float4*)(Z + (size_t)node * 64 + c4);
    float4 o = make_float4(ax + self.x, ay + self.y, az + self.z, aw + self.w);
    *(float4*)(G + (size_t)node * 64 + c4) = o;
  }
}

// sc/sh from bns, then W'[k][c] = sc[k]*W[k][c] (64x64), c'[c] = sum_k sh[k]*W[k][c].
__global__ __launch_bounds__(256) void prep_small(
    const float* __restrict__ bns, const float* __restrict__ g,
    const float* __restrict__ be, const float* __restrict__ W,
    float* __restrict__ Wc, float* __restrict__ cx, float invN) {
  __shared__ float sc[64], sh[64], part[4][64];
  int t = threadIdx.x;
  if (t < 64) {
    float mean = bns[t] * invN;
    float var = bns[64 + t] * invN - mean * mean;
    float s = g[t] * rsqrtf(var + BN_EPS);
    sc[t] = s;
    sh[t] = be[t] - mean * s;
  }
  __syncthreads();
  int c = t & 63, kq = t >> 6;
  float p = 0.f;
  for (int k = kq * 16; k < kq * 16 + 16; ++k) {
    float w = W[k * 64 + c];
    Wc[k * 64 + c] = sc[k] * w;
    p += sh[k] * w;
  }
  part[kq][c] = p;
  __syncthreads();
  if (t < 64) cx[t] = part[0][t] + part[1][t] + part[2][t] + part[3][t];
}

// Same for the two 64x768 head weights. grid.x = 12: 0-5 mu, 6-11 ls (128 cols each).
__global__ __launch_bounds__(256) void prep_head(
    const float* __restrict__ bns, const float* __restrict__ g,
    const float* __restrict__ be, const float* __restrict__ Wmu,
    const float* __restrict__ Wls, float* __restrict__ Wmc,
    float* __restrict__ Wlc, float* __restrict__ cmu, float* __restrict__ cls,
    float invN) {
  __shared__ float sc[64], sh[64], part[2][128];
  int t = threadIdx.x;
  if (t < 64) {
    float mean = bns[t] * invN;
    float var = bns[64 + t] * invN - mean * mean;
    float s = g[t] * rsqrtf(var + BN_EPS);
    sc[t] = s;
    sh[t] = be[t] - mean * s;
  }
  __syncthreads();
  int blk = blockIdx.x;
  int head = blk >= 6 ? 1 : 0;
  int c0 = (head ? blk - 6 : blk) * 128;
  const float* W = head ? Wls : Wmu;
  float* Wc = head ? Wlc : Wmc;
  float* cx = head ? cls : cmu;
  int c = c0 + (t & 127), kh = t >> 7;
  float p = 0.f;
  for (int k = kh * 32; k < kh * 32 + 32; ++k) {
    float w = W[(size_t)k * 768 + c];
    Wc[(size_t)k * 768 + c] = sc[k] * w;
    p += sh[k] * w;
  }
  part[kh][t & 127] = p;
  __syncthreads();
  if (t < 128) cx[c0 + t] = part[0][t] + part[1][t];
}

// Layers 2/3 GEMM (split from gather): Z_next = LeakyReLU(dv*(G @ Wc) +
// dv*q[r]*cx + b) * dv, plus BN stats of o. 64x64 tile, 4x4/thread.
__global__ __launch_bounds__(256, 4) void gemm_bnq(
    const float* __restrict__ G, const float* __restrict__ dinv,
    const float* __restrict__ q, const float* __restrict__ Wc,
    const float* __restrict__ cx, const float* __restrict__ b,
    float* __restrict__ Z, float* __restrict__ bns, int N) {
  __shared__ __align__(16) float P[64][68];
  __shared__ __align__(16) float Ws[64][64];
  const int t = threadIdx.x;
  const int r0 = blockIdx.x * 64;

  for (int i = t; i < 1024; i += 256) {
    int r = i >> 4, k4 = (i & 15) << 2, gr = r0 + r;
    float4 v = make_float4(0.f, 0.f, 0.f, 0.f);
    if (gr < N) v = *(const float4*)(G + (size_t)gr * 64 + k4);
    *(float4*)&P[r][k4] = v;
  }
  for (int i = t; i < 4096; i += 256) Ws[i >> 6][i & 63] = Wc[i];
  __syncthreads();

  const int tr = t >> 4, tc4 = (t & 15) << 2;
  float acc[4][4] = {};
#pragma unroll 8
  for (int k = 0; k < 64; ++k) {
    float4 w = *(const float4*)&Ws[k][tc4];
#pragma unroll
    for (int i = 0; i < 4; ++i) {
      float a = P[tr + 16 * i][k];
      acc[i][0] += a * w.x;
      acc[i][1] += a * w.y;
      acc[i][2] += a * w.z;
      acc[i][3] += a * w.w;
    }
  }

  float s1[4] = {0.f, 0.f, 0.f, 0.f}, s2[4] = {0.f, 0.f, 0.f, 0.f};
  float4 bb = *(const float4*)(b + tc4);
  float4 cc = *(const float4*)(cx + tc4);
#pragma unroll
  for (int i = 0; i < 4; ++i) {
    int r = r0 + tr + 16 * i;
    if (r < N) {
      float dv = dinv[r];
      float dq = dv * q[r];
      float u0 = acc[i][0] * dv + dq * cc.x + bb.x;
      float u1 = acc[i][1] * dv + dq * cc.y + bb.y;
      float u2 = acc[i][2] * dv + dq * cc.z + bb.z;
      float u3 = acc[i][3] * dv + dq * cc.w + bb.w;
      float o0 = u0 >= 0.f ? u0 : NEG_SLOPE * u0;
      float o1 = u1 >= 0.f ? u1 : NEG_SLOPE * u1;
      float o2 = u2 >= 0.f ? u2 : NEG_SLOPE * u2;
      float o3 = u3 >= 0.f ? u3 : NEG_SLOPE * u3;
      float4 z = make_float4(o0 * dv, o1 * dv, o2 * dv, o3 * dv);
      *(float4*)(Z + (size_t)r * 64 + tc4) = z;
      s1[0] += o0; s2[0] += o0 * o0;
      s1[1] += o1; s2[1] += o1 * o1;
      s1[2] += o2; s2[2] += o2 * o2;
      s1[3] += o3; s2[3] += o3 * o3;
    }
  }
  __syncthreads();  // Ws no longer needed; reuse for BN reduction
  float (*red1)[64] = (float(*)[64]) & Ws[0][0];
  float (*red2)[64] = (float(*)[64]) & Ws[16][0];
#pragma unroll
  for (int j = 0; j < 4; ++j) {
    red1[tr][tc4 + j] = s1[j];
    red2[tr][tc4 + j] = s2[j];
  }
  __syncthreads();
  if (t < 64) {
    float a1 = 0.f, a2 = 0.f;
#pragma unroll
    for (int i = 0; i < 16; ++i) {
      a1 += red1[i][t];
      a2 += red2[i][t];
    }
    atomicAdd(&bns[t], a1);
    atomicAdd(&bns[64 + t], a2);
  }
}

// Heads, 128 rows x 128 cols per block (8x8 per thread); grid y: 0-5 mu,
// 6-11 ls. out = dv*(G @ Wc) + dv*q[r]*cx + b. LDS 50KB -> 3 blocks/CU.
__global__ __launch_bounds__(256, 3) void head_gemm3(
    const float* __restrict__ G, const float* __restrict__ dinv,
    const float* __restrict__ q, const float* __restrict__ Wmc,
    const float* __restrict__ cmu, const float* __restrict__ bmu,
    const float* __restrict__ Wlc, const float* __restrict__ cls,
    const float* __restrict__ bls, float* __restrict__ OUT, int N) {
  __shared__ __align__(16) float P[128][68];
  __shared__ __align__(16) float Ws[32][128];
  const int t = threadIdx.x;
  const int r0 = blockIdx.x * 128;
  const int yy = blockIdx.y;
  const int head = (yy >= 6) ? 1 : 0;
  const int c0 = (head ? yy - 6 : yy) * 128;
  const float* W = head ? Wlc : Wmc;
  const float* cx = head ? cls : cmu;
  const float* b = head ? bls : bmu;
  float* O = OUT + (head ? (size_t)N * 768 : 0);

  for (int i = t; i < 2048; i += 256) {
    int r = i >> 4, k4 = (i & 15) << 2, gr = r0 + r;
    float4 v = make_float4(0.f, 0.f, 0.f, 0.f);
    if (gr < N) v = *(const float4*)(G + (size_t)gr * 64 + k4);
    *(float4*)&P[r][k4] = v;
  }

  const int tr = t >> 4;   // rows tr + 16*i, i = 0..7
  const int tc = t & 15;   // cols c0 + tc*4 (+0 / +64)
  float acc[8][8] = {};

  for (int kk = 0; kk < 64; kk += 32) {
    __syncthreads();  // first also covers P readiness
    for (int i = t; i < 1024; i += 256) {  // 32 k x 128 c as float4s
      int k = i >> 5, c4 = (i & 31) << 2;
      *(float4*)&Ws[k][c4] = *(const float4*)(W + (size_t)(kk + k) * 768 + c0 + c4);
    }
    __syncthreads();
#pragma unroll 2
    for (int k = 0; k < 32; ++k) {
      float4 w0 = *(const float4*)&Ws[k][tc * 4];
      float4 w1 = *(const float4*)&Ws[k][64 + tc * 4];
#pragma unroll
      for (int i = 0; i < 8; ++i) {
        float a = P[tr + 16 * i][kk + k];
        acc[i][0] += a * w0.x;
        acc[i][1] += a * w0.y;
        acc[i][2] += a * w0.z;
        acc[i][3] += a * w0.w;
        acc[i][4] += a * w1.x;
        acc[i][5] += a * w1.y;
        acc[i][6] += a * w1.z;
        acc[i][7] += a * w1.w;
      }
    }
  }

  float4 bb0 = *(const float4*)(b + c0 + tc * 4);
  float4 bb1 = *(const float4*)(b + c0 + 64 + tc * 4);
  float4 cc0 = *(const float4*)(cx + c0 + tc * 4);
  float4 cc1 = *(const float4*)(cx + c0 + 64 + tc * 4);
#pragma unroll
  for (int i = 0; i < 8; ++i) {
    int r = r0 + tr + 16 * i;
    if (r < N) {
      float dv = dinv[r];
      float dq = dv * q[r];
      float4 o0 = make_float4(acc[i][0] * dv + dq * cc0.x + bb0.x,
                              acc[i][1] * dv + dq * cc0.y + bb0.y,
                              acc[i][2] * dv + dq * cc0.z + bb0.z,
                              acc[i][3] * dv + dq * cc0.w + bb0.w);
      float4 o1 = make_float4(acc[i][4] * dv + dq * cc1.x + bb1.x,
                              acc[i][5] * dv + dq * cc1.y + bb1.y,
                              acc[i][6] * dv + dq * cc1.z + bb1.z,
                              acc[i][7] * dv + dq * cc1.w + bb1.w);
      *(float4*)(O + (size_t)r * 768 + c0 + tc * 4) = o0;
      *(float4*)(O + (size_t)r * 768 + c0 + 64 + tc * 4) = o1;
    }
  }
}

extern "C" void kernel_launch(void* const* d_in, const int* in_sizes, int n_in,
                              void* d_out, int out_size, void* d_ws, size_t ws_size,
                              hipStream_t stream) {
  const float* x   = (const float*)d_in[0];
  const int*   ei  = (const int*)d_in[1];
  const float* W1  = (const float*)d_in[2];
  const float* b1  = (const float*)d_in[3];
  const float* g1  = (const float*)d_in[4];
  const float* be1 = (const float*)d_in[5];
  const float* W2  = (const float*)d_in[6];
  const float* b2  = (const float*)d_in[7];
  const float* g2  = (const float*)d_in[8];
  const float* be2 = (const float*)d_in[9];
  const float* W3  = (const float*)d_in[10];
  const float* b3  = (const float*)d_in[11];
  const float* g3  = (const float*)d_in[12];
  const float* be3 = (const float*)d_in[13];
  const float* Wmu = (const float*)d_in[14];
  const float* bmu = (const float*)d_in[15];
  const float* Wls = (const float*)d_in[16];
  const float* bls = (const float*)d_in[17];

  const int N = in_sizes[0] / 3;
  const int E = in_sizes[1] / 2;
  const int* src = ei;
  const int* dst = ei + E;
  float* out = (float*)d_out;

  char* ws = (char*)d_ws;
  size_t o = 0;
  float* dinv = (float*)(ws + o); o += (size_t)N * 4;
  float* qv   = (float*)(ws + o); o += (size_t)N * 4;
  float* bns  = (float*)(ws + o); o += 384 * 4;
  float* W2c  = (float*)(ws + o); o += 4096 * 4;
  float* c2   = (float*)(ws + o); o += 64 * 4;
  float* W3c  = (float*)(ws + o); o += 4096 * 4;
  float* c3   = (float*)(ws + o); o += 64 * 4;
  float* Wmc  = (float*)(ws + o); o += (size_t)64 * 768 * 4;
  float* cmu  = (float*)(ws + o); o += 768 * 4;
  float* Wlc  = (float*)(ws + o); o += (size_t)64 * 768 * 4;
  float* cls  = (float*)(ws + o); o += 768 * 4;
  int* cnt    = (int*)(ws + o);   o += (size_t)N * 4;
  int* rowptr = (int*)(ws + o);   o += ((size_t)N + 1) * 4;
  int* cursor = (int*)(ws + o);   o += (size_t)N * 4;
  int* bsum   = (int*)(ws + o);   o += 64 * 4;
  int* eidx   = (int*)(ws + o);   o += (size_t)E * 4;
  float* B0   = (float*)(ws + o); o += (size_t)N * 64 * 4;
  float* B1   = (float*)(ws + o); o += (size_t)N * 64 * 4;
  // ws_size observed ~1.2 GB; total used ~31 MB.

  const float invN = 1.0f / (float)N;
  int nbN = (N + 255) / 256;
  int nbE = (E + 255) / 256;
  int gb  = (N + 63) / 64;
  int gb2 = (N + 127) / 128;
  int wb  = (N + 3) / 4;
  int sbA = (N + 1023) / 1024;

  // CSR build (edge_index constant across all 4 propagations)
  init_k<<<nbN, 256, 0, stream>>>(cnt, bns, N);
  hist_k<<<nbE, 256, 0, stream>>>(dst, cnt, E);
  scanA<<<sbA, 1024, 0, stream>>>(cnt, rowptr, bsum, N);
  scanB<<<1, 64, 0, stream>>>(bsum, sbA);
  scanC<<<nbN, 256, 0, stream>>>(cnt, rowptr, cursor, bsum, dinv, N, E);
  fill_k<<<nbE, 256, 0, stream>>>(src, dst, cursor, eidx, E);

  // ---- layer 1: fused gather(3ch)+GEMM+stats, writes Z1=B0 and q ----
  l1_fused<<<1024, 256, 0, stream>>>(rowptr, eidx, x, dinv, W1, b1, B0, qv, bns, N);
  prep_small<<<1, 256, 0, stream>>>(bns + 0, g1, be1, W2, W2c, c2, invN);

  // ---- layer 2 (split gather -> GEMM) ----
  gather64<<<wb, 256, 0, stream>>>(rowptr, eidx, B0, B1, N);      // B1 = G1
  gemm_bnq<<<gb, 256, 0, stream>>>(B1, dinv, qv, W2c, c2, b2, B0, bns + 128, N);
  prep_small<<<1, 256, 0, stream>>>(bns + 128, g2, be2, W3, W3c, c3, invN);

  // ---- layer 3 ----
  gather64<<<wb, 256, 0, stream>>>(rowptr, eidx, B0, B1, N);      // B1 = G2
  gemm_bnq<<<gb, 256, 0, stream>>>(B1, dinv, qv, W3c, c3, b3, B0, bns + 256, N);
  prep_head<<<12, 256, 0, stream>>>(bns + 256, g3, be3, Wmu, Wls, Wmc, Wlc, cmu, cls, invN);

  // ---- final propagate + 128x128-tile head GEMM ----
  gather64<<<wb, 256, 0, stream>>>(rowptr, eidx, B0, B1, N);      // B1 = G3
  dim3 hgrid(gb2, 12);
  head_gemm3<<<hgrid, 256, 0, stream>>>(B1, dinv, qv, Wmc, cmu, bmu, Wlc, cls, bls, out, N);
}

// Round 13
// 427.586 us; speedup vs baseline: 1.1459x; 1.0311x over previous
//
#include <hip/hip_runtime.h>
#include <cstddef>

// GCN encoder, BN-folded, split gather->GEMM (fusion measured net-negative
// r10/r11). Head GEMM now runs on MFMA via split-bf16 (hi+lo), r13:
// D = Ah*Bh + Ah*Bl + Al*Bh  (drops Al*Bl ~ 2^-16 rel).
// prop(h)[d] = dinv[d]*(P(h)[d] @ W) + b; BN folded via W'=diag(sc)W, c'=sh@W,
// q[d] = sum dinv; epilogue u = dv*acc + dv*q[r]*c'[c] + b[c].

#define NEG_SLOPE 0.01f
#define BN_EPS 1e-5f

typedef unsigned short u16;
typedef __attribute__((ext_vector_type(8))) short bf16x8;
typedef __attribute__((ext_vector_type(4))) float f32x4;

__device__ __forceinline__ unsigned bf16_rne(float x) {
  unsigned u = __float_as_uint(x);
  return (u + 0x7fffu + ((u >> 16) & 1u)) >> 16;
}

__global__ __launch_bounds__(256) void init_k(int* __restrict__ cnt,
                                              float* __restrict__ bns, int N) {
  int i = blockIdx.x * 256 + threadIdx.x;
  if (i < N) cnt[i] = 0;
  if (i < 384) bns[i] = 0.0f;  // 3 layers x {sum[64], sumsq[64]}
}

__global__ __launch_bounds__(256) void hist_k(const int* __restrict__ dst,
                                              int* __restrict__ cnt, int E) {
  int e = blockIdx.x * 256 + threadIdx.x;
  if (e < E) atomicAdd(&cnt[dst[e]], 1);
}

__global__ __launch_bounds__(1024) void scanA(const int* __restrict__ cnt,
                                              int* __restrict__ pre,
                                              int* __restrict__ bsum, int N) {
  __shared__ int sh[1024];
  const int t = threadIdx.x;
  const int i = blockIdx.x * 1024 + t;
  int c = (i < N) ? cnt[i] : 0;
  sh[t] = c;
  __syncthreads();
  for (int off = 1; off < 1024; off <<= 1) {
    int v = (t >= off) ? sh[t - off] : 0;
    __syncthreads();
    sh[t] += v;
    __syncthreads();
  }
  if (i < N) pre[i] = sh[t] - c;  // exclusive
  if (t == 1023) bsum[blockIdx.x] = sh[t];
}

__global__ __launch_bounds__(64) void scanB(int* __restrict__ bsum, int nb) {
  int t = threadIdx.x;
  int orig = (t < nb) ? bsum[t] : 0;
  int v = orig;
#pragma unroll
  for (int off = 1; off < 64; off <<= 1) {
    int u = __shfl_up(v, off);
    if (t >= off) v += u;
  }
  if (t < nb) bsum[t] = v - orig;
}

__global__ __launch_bounds__(256) void scanC(const int* __restrict__ cnt,
                                             int* __restrict__ rowptr,
                                             int* __restrict__ cursor,
                                             const int* __restrict__ bsum,
                                             float* __restrict__ dinv,
                                             int N, int E) {
  int i = blockIdx.x * 256 + threadIdx.x;
  if (i < N) {
    int rp = rowptr[i] + bsum[i >> 10];
    rowptr[i] = rp;
    cursor[i] = rp;
    dinv[i] = rsqrtf((float)(cnt[i] + 1));  // +1 self loop
  }
  if (i == 0) rowptr[N] = E;
}

__global__ __launch_bounds__(256) void fill_k(const int* __restrict__ src,
                                              const int* __restrict__ dst,
                                              int* __restrict__ cursor,
                                              int* __restrict__ eidx, int E) {
  int e = blockIdx.x * 256 + threadIdx.x;
  if (e >= E) return;
  int p = atomicAdd(&cursor[dst[e]], 1);
  eidx[p] = src[e];
}

// Layer 1 fully fused (3ch gather + 3->64 matvec + stats + q).
__global__ __launch_bounds__(256) void l1_fused(
    const int* __restrict__ rowptr, const int* __restrict__ eidx,
    const float* __restrict__ x, const float* __restrict__ dinv,
    const float* __restrict__ W1, const float* __restrict__ b1,
    float* __restrict__ Z, float* __restrict__ q, float* __restrict__ bns, int N) {
  const int t = threadIdx.x, lane = t & 63, wid = t >> 6;
  const int gw = blockIdx.x * 4 + wid;
  const int nw = gridDim.x * 4;
  const float w0 = W1[lane], w1 = W1[64 + lane], w2 = W1[128 + lane];
  const float bb = b1[lane];
  float s1 = 0.f, s2 = 0.f;
  for (int node = gw; node < N; node += nw) {
    int beg = rowptr[node], end = rowptr[node + 1];
    float a0 = 0.f, a1 = 0.f, a2 = 0.f, aq = 0.f;
    for (int e = beg + lane; e < end; e += 64) {
      int s = eidx[e];
      float dv = dinv[s];
      a0 += x[s * 3] * dv;
      a1 += x[s * 3 + 1] * dv;
      a2 += x[s * 3 + 2] * dv;
      aq += dv;
    }
#pragma unroll
    for (int off = 32; off; off >>= 1) {
      a0 += __shfl_xor(a0, off);
      a1 += __shfl_xor(a1, off);
      a2 += __shfl_xor(a2, off);
      aq += __shfl_xor(aq, off);
    }
    float dv = dinv[node];
    a0 += x[node * 3] * dv;
    a1 += x[node * 3 + 1] * dv;
    a2 += x[node * 3 + 2] * dv;
    aq += dv;
    float u = dv * (a0 * w0 + a1 * w1 + a2 * w2) + bb;
    float o = u >= 0.f ? u : NEG_SLOPE * u;
    Z[(size_t)node * 64 + lane] = o * dv;
    s1 += o;
    s2 += o * o;
    if (lane == 0) q[node] = aq;
  }
  __shared__ float red[8][64];
  red[wid][lane] = s1;
  red[4 + wid][lane] = s2;
  __syncthreads();
  if (t < 64) {
    atomicAdd(&bns[t], red[0][t] + red[1][t] + red[2][t] + red[3][t]);
    atomicAdd(&bns[64 + t], red[4][t] + red[5][t] + red[6][t] + red[7][t]);
  }
}

// Standalone gather: G[node][c] = Z[node][c] + sum Z[src][c]; one wave/node.
__global__ __launch_bounds__(256) void gather64(const int* __restrict__ rowptr,
                                                const int* __restrict__ eidx,
                                                const float* __restrict__ Z,
                                                float* __restrict__ G, int N) {
  int node = blockIdx.x * 4 + (threadIdx.x >> 6);
  if (node >= N) return;
  int lane = threadIdx.x & 63;
  int slot = lane >> 4;
  int c4 = (lane & 15) << 2;
  int beg = rowptr[node], end = rowptr[node + 1];
  float ax = 0.f, ay = 0.f, az = 0.f, aw = 0.f;
  int e = beg + slot;
  for (; e + 4 < end; e += 8) {
    int s0 = eidx[e], s1 = eidx[e + 4];
    float4 v0 = *(const float4*)(Z + (size_t)s0 * 64 + c4);
    float4 v1 = *(const float4*)(Z + (size_t)s1 * 64 + c4);
    ax += v0.x + v1.x;
    ay += v0.y + v1.y;
    az += v0.z + v1.z;
    aw += v0.w + v1.w;
  }
  if (e < end) {
    int s0 = eidx[e];
    float4 v0 = *(const float4*)(Z + (size_t)s0 * 64 + c4);
    ax += v0.x; ay += v0.y; az += v0.z; aw += v0.w;
  }
#pragma unroll
  for (int off = 16; off < 64; off <<= 1) {
    ax += __shfl_xor(ax, off);
    ay += __shfl_xor(ay, off);
    az += __shfl_xor(az, off);
    aw += __shfl_xor(aw, off);
  }
  if (slot == 0) {
    float4 self = *(const float4*)(Z + (size_t)node * 64 + c4);
    float4 o = make_float4(ax + self.x, ay + self.y, az + self.z, aw + self.w);
    *(float4*)(G + (size_t)node * 64 + c4) = o;
  }
}

// Final gather: same, but writes packed split-bf16 (hi/lo) for the MFMA head.
__global__ __launch_bounds__(256) void gather64h(const int* __restrict__ rowptr,
                                                 const int* __restrict__ eidx,
                                                 const float* __restrict__ Z,
                                                 u16* __restrict__ Ghi,
                                                 u16* __restrict__ Glo, int N) {
  int node = blockIdx.x * 4 + (threadIdx.x >> 6);
  if (node >= N) return;
  int lane = threadIdx.x & 63;
  int slot = lane >> 4;
  int c4 = (lane & 15) << 2;
  int beg = rowptr[node], end = rowptr[node + 1];
  float ax = 0.f, ay = 0.f, az = 0.f, aw = 0.f;
  int e = beg + slot;
  for (; e + 4 < end; e += 8) {
    int s0 = eidx[e], s1 = eidx[e + 4];
    float4 v0 = *(const float4*)(Z + (size_t)s0 * 64 + c4);
    float4 v1 = *(const float4*)(Z + (size_t)s1 * 64 + c4);
    ax += v0.x + v1.x;
    ay += v0.y + v1.y;
    az += v0.z + v1.z;
    aw += v0.w + v1.w;
  }
  if (e < end) {
    int s0 = eidx[e];
    float4 v0 = *(const float4*)(Z + (size_t)s0 * 64 + c4);
    ax += v0.x; ay += v0.y; az += v0.z; aw += v0.w;
  }
#pragma unroll
  for (int off = 16; off < 64; off <<= 1) {
    ax += __shfl_xor(ax, off);
    ay += __shfl_xor(ay, off);
    az += __shfl_xor(az, off);
    aw += __shfl_xor(aw, off);
  }
  if (slot == 0) {
    float4 self = *(const float4*)(Z + (size_t)node * 64 + c4);
    float o0 = ax + self.x, o1 = ay + self.y, o2 = az + self.z, o3 = aw + self.w;
    unsigned h0 = bf16_rne(o0), h1 = bf16_rne(o1), h2 = bf16_rne(o2), h3 = bf16_rne(o3);
    unsigned l0 = bf16_rne(o0 - __uint_as_float(h0 << 16));
    unsigned l1 = bf16_rne(o1 - __uint_as_float(h1 << 16));
    unsigned l2 = bf16_rne(o2 - __uint_as_float(h2 << 16));
    unsigned l3 = bf16_rne(o3 - __uint_as_float(h3 << 16));
    uint2 hv = make_uint2(h0 | (h1 << 16), h2 | (h3 << 16));
    uint2 lv = make_uint2(l0 | (l1 << 16), l2 | (l3 << 16));
    *(uint2*)(Ghi + (size_t)node * 64 + c4) = hv;
    *(uint2*)(Glo + (size_t)node * 64 + c4) = lv;
  }
}

// sc/sh from bns, then W'[k][c] = sc[k]*W[k][c] (64x64), c'[c] = sum_k sh[k]*W[k][c].
__global__ __launch_bounds__(256) void prep_small(
    const float* __restrict__ bns, const float* __restrict__ g,
    const float* __restrict__ be, const float* __restrict__ W,
    float* __restrict__ Wc, float* __restrict__ cx, float invN) {
  __shared__ float sc[64], sh[64], part[4][64];
  int t = threadIdx.x;
  if (t < 64) {
    float mean = bns[t] * invN;
    float var = bns[64 + t] * invN - mean * mean;
    float s = g[t] * rsqrtf(var + BN_EPS);
    sc[t] = s;
    sh[t] = be[t] - mean * s;
  }
  __syncthreads();
  int c = t & 63, kq = t >> 6;
  float p = 0.f;
  for (int k = kq * 16; k < kq * 16 + 16; ++k) {
    float w = W[k * 64 + c];
    Wc[k * 64 + c] = sc[k] * w;
    p += sh[k] * w;
  }
  part[kq][c] = p;
  __syncthreads();
  if (t < 64) cx[t] = part[0][t] + part[1][t] + part[2][t] + part[3][t];
}

// Head weight prep: cx = sh@W, and W' = sc[k]*W packed as split-bf16 in
// MFMA B-fragment order: B[k][col]: lane = ((k>>3)&3)*16 + (col&15), j = k&7.
// Bh/Bl index: [(head*6+cc)][p=k>>5][ct=colchunk>>4][lane][j].
// grid.x = 12: blocks 0-5 mu, 6-11 ls (128 cols each).
__global__ __launch_bounds__(256) void prep_head(
    const float* __restrict__ bns, const float* __restrict__ g,
    const float* __restrict__ be, const float* __restrict__ Wmu,
    const float* __restrict__ Wls, u16* __restrict__ Bh, u16* __restrict__ Bl,
    float* __restrict__ cmu, float* __restrict__ cls, float invN) {
  __shared__ float sc[64], sh[64], part[2][128];
  int t = threadIdx.x;
  if (t < 64) {
    float mean = bns[t] * invN;
    float var = bns[64 + t] * invN - mean * mean;
    float s = g[t] * rsqrtf(var + BN_EPS);
    sc[t] = s;
    sh[t] = be[t] - mean * s;
  }
  __syncthreads();
  int blk = blockIdx.x;
  int head = blk >= 6 ? 1 : 0;
  int cc = head ? blk - 6 : blk;
  int c0 = cc * 128;
  const float* W = head ? Wls : Wmu;
  float* cx = head ? cls : cmu;
  int cl = t & 127, kh = t >> 7;
  int c = c0 + cl;
  int ct = cl >> 4, jc = cl & 15;
  size_t base = (size_t)(head * 6 + cc) * 2 * 8 * 64 * 8;
  float p = 0.f;
  for (int k = kh * 32; k < kh * 32 + 32; ++k) {
    float w = W[(size_t)k * 768 + c];
    float wc = sc[k] * w;
    p += sh[k] * w;
    unsigned hi = bf16_rne(wc);
    unsigned lo = bf16_rne(wc - __uint_as_float(hi << 16));
    int lane = ((k >> 3) & 3) * 16 + jc;
    size_t idx = base + (((size_t)kh * 8 + ct) * 64 + lane) * 8 + (k & 7);
    Bh[idx] = (u16)hi;
    Bl[idx] = (u16)lo;
  }
  part[kh][cl] = p;
  __syncthreads();
  if (t < 128) cx[c0 + t] = part[0][t] + part[1][t];
}

// Layers 2/3 GEMM (split from gather), 64x64 tile, 4x4/thread, fp32.
__global__ __launch_bounds__(256, 4) void gemm_bnq(
    const float* __restrict__ G, const float* __restrict__ dinv,
    const float* __restrict__ q, const float* __restrict__ Wc,
    const float* __restrict__ cx, const float* __restrict__ b,
    float* __restrict__ Z, float* __restrict__ bns, int N) {
  __shared__ __align__(16) float P[64][68];
  __shared__ __align__(16) float Ws[64][64];
  const int t = threadIdx.x;
  const int r0 = blockIdx.x * 64;

  for (int i = t; i < 1024; i += 256) {
    int r = i >> 4, k4 = (i & 15) << 2, gr = r0 + r;
    float4 v = make_float4(0.f, 0.f, 0.f, 0.f);
    if (gr < N) v = *(const float4*)(G + (size_t)gr * 64 + k4);
    *(float4*)&P[r][k4] = v;
  }
  for (int i = t; i < 4096; i += 256) Ws[i >> 6][i & 63] = Wc[i];
  __syncthreads();

  const int tr = t >> 4, tc4 = (t & 15) << 2;
  float acc[4][4] = {};
#pragma unroll 8
  for (int k = 0; k < 64; ++k) {
    float4 w = *(const float4*)&Ws[k][tc4];
#pragma unroll
    for (int i = 0; i < 4; ++i) {
      float a = P[tr + 16 * i][k];
      acc[i][0] += a * w.x;
      acc[i][1] += a * w.y;
      acc[i][2] += a * w.z;
      acc[i][3] += a * w.w;
    }
  }

  float s1[4] = {0.f, 0.f, 0.f, 0.f}, s2[4] = {0.f, 0.f, 0.f, 0.f};
  float4 bb = *(const float4*)(b + tc4);
  float4 cc = *(const float4*)(cx + tc4);
#pragma unroll
  for (int i = 0; i < 4; ++i) {
    int r = r0 + tr + 16 * i;
    if (r < N) {
      float dv = dinv[r];
      float dq = dv * q[r];
      float u0 = acc[i][0] * dv + dq * cc.x + bb.x;
      float u1 = acc[i][1] * dv + dq * cc.y + bb.y;
      float u2 = acc[i][2] * dv + dq * cc.z + bb.z;
      float u3 = acc[i][3] * dv + dq * cc.w + bb.w;
      float o0 = u0 >= 0.f ? u0 : NEG_SLOPE * u0;
      float o1 = u1 >= 0.f ? u1 : NEG_SLOPE * u1;
      float o2 = u2 >= 0.f ? u2 : NEG_SLOPE * u2;
      float o3 = u3 >= 0.f ? u3 : NEG_SLOPE * u3;
      float4 z = make_float4(o0 * dv, o1 * dv, o2 * dv, o3 * dv);
      *(float4*)(Z + (size_t)r * 64 + tc4) = z;
      s1[0] += o0; s2[0] += o0 * o0;
      s1[1] += o1; s2[1] += o1 * o1;
      s1[2] += o2; s2[2] += o2 * o2;
      s1[3] += o3; s2[3] += o3 * o3;
    }
  }
  __syncthreads();  // Ws no longer needed; reuse for BN reduction
  float (*red1)[64] = (float(*)[64]) & Ws[0][0];
  float (*red2)[64] = (float(*)[64]) & Ws[16][0];
#pragma unroll
  for (int j = 0; j < 4; ++j) {
    red1[tr][tc4 + j] = s1[j];
    red2[tr][tc4 + j] = s2[j];
  }
  __syncthreads();
  if (t < 64) {
    float a1 = 0.f, a2 = 0.f;
#pragma unroll
    for (int i = 0; i < 16; ++i) {
      a1 += red1[i][t];
      a2 += red2[i][t];
    }
    atomicAdd(&bns[t], a1);
    atomicAdd(&bns[64 + t], a2);
  }
}

// MFMA head: split-bf16, no LDS, no barriers. Block = 4 waves; wave = 16 rows
// x 128 cols (8 col-tiles x 6 mfma_f32_16x16x32_bf16 each). Grid (N/64, 12).
// Layouts (HW-verified m89/m162): A row=l&15 k=(l>>4)*8+j; B col=l&15 same k;
// D col=l&15 row=(l>>4)*4+reg.
__global__ __launch_bounds__(256) void head_mfma(
    const u16* __restrict__ Ghi, const u16* __restrict__ Glo,
    const float* __restrict__ dinv, const float* __restrict__ q,
    const u16* __restrict__ Bh, const u16* __restrict__ Bl,
    const float* __restrict__ cmu, const float* __restrict__ bmu,
    const float* __restrict__ cls, const float* __restrict__ bls,
    float* __restrict__ OUT, int N) {
  const int t = threadIdx.x;
  const int w = t >> 6, l = t & 63;
  const int r0 = blockIdx.x * 64 + w * 16;
  const int yy = blockIdx.y;
  const int head = (yy >= 6) ? 1 : 0;
  const int cc = head ? yy - 6 : yy;
  const int c0 = cc * 128;
  const float* cx = head ? cls : cmu;
  const float* bb = head ? bls : bmu;
  float* O = OUT + (head ? (size_t)N * 768 : 0);

  int arow = r0 + (l & 15);
  if (arow >= N) arow = N - 1;  // clamped load; stores guarded below
  const u16* gh = Ghi + (size_t)arow * 64 + ((l >> 4) << 3);
  const u16* gl = Glo + (size_t)arow * 64 + ((l >> 4) << 3);
  const bf16x8 ah0 = *(const bf16x8*)gh;
  const bf16x8 ah1 = *(const bf16x8*)(gh + 32);
  const bf16x8 al0 = *(const bf16x8*)gl;
  const bf16x8 al1 = *(const bf16x8*)(gl + 32);

  const size_t base = (size_t)(head * 6 + cc) * 2 * 8 * 64 * 8;
  const u16* bhp = Bh + base;
  const u16* blp = Bl + base;

  f32x4 acc[8];
#pragma unroll
  for (int ct = 0; ct < 8; ++ct) {
    const bf16x8 bh0 = *(const bf16x8*)(bhp + (((size_t)ct) * 64 + l) * 8);
    const bf16x8 bh1 = *(const bf16x8*)(bhp + (((size_t)(8 + ct)) * 64 + l) * 8);
    const bf16x8 bl0 = *(const bf16x8*)(blp + (((size_t)ct) * 64 + l) * 8);
    const bf16x8 bl1 = *(const bf16x8*)(blp + (((size_t)(8 + ct)) * 64 + l) * 8);
    f32x4 a = {0.f, 0.f, 0.f, 0.f};
    a = __builtin_amdgcn_mfma_f32_16x16x32_bf16(ah0, bh0, a, 0, 0, 0);
    a = __builtin_amdgcn_mfma_f32_16x16x32_bf16(ah1, bh1, a, 0, 0, 0);
    a = __builtin_amdgcn_mfma_f32_16x16x32_bf16(ah0, bl0, a, 0, 0, 0);
    a = __builtin_amdgcn_mfma_f32_16x16x32_bf16(ah1, bl1, a, 0, 0, 0);
    a = __builtin_amdgcn_mfma_f32_16x16x32_bf16(al0, bh0, a, 0, 0, 0);
    a = __builtin_amdgcn_mfma_f32_16x16x32_bf16(al1, bh1, a, 0, 0, 0);
    acc[ct] = a;
  }

  const int jc = l & 15;
  const int rbase = r0 + ((l >> 4) << 2);
  float dv[4], dq[4];
#pragma unroll
  for (int r = 0; r < 4; ++r) {
    int row = rbase + r;
    int rc = row < N ? row : N - 1;
    dv[r] = dinv[rc];
    dq[r] = dv[r] * q[rc];
  }
#pragma unroll
  for (int ct = 0; ct < 8; ++ct) {
    int col = c0 + ct * 16 + jc;
    float cxv = cx[col], bbv = bb[col];
#pragma unroll
    for (int r = 0; r < 4; ++r) {
      int row = rbase + r;
      if (row < N)
        O[(size_t)row * 768 + col] = acc[ct][r] * dv[r] + dq[r] * cxv + bbv;
    }
  }
}

extern "C" void kernel_launch(void* const* d_in, const int* in_sizes, int n_in,
                              void* d_out, int out_size, void* d_ws, size_t ws_size,
                              hipStream_t stream) {
  const float* x   = (const float*)d_in[0];
  const int*   ei  = (const int*)d_in[1];
  const float* W1  = (const float*)d_in[2];
  const float* b1  = (const float*)d_in[3];
  const float* g1  = (const float*)d_in[4];
  const float* be1 = (const float*)d_in[5];
  const float* W2  = (const float*)d_in[6];
  const float* b2  = (const float*)d_in[7];
  const float* g2  = (const float*)d_in[8];
  const float* be2 = (const float*)d_in[9];
  const float* W3  = (const float*)d_in[10];
  const float* b3  = (const float*)d_in[11];
  const float* g3  = (const float*)d_in[12];
  const float* be3 = (const float*)d_in[13];
  const float* Wmu = (const float*)d_in[14];
  const float* bmu = (const float*)d_in[15];
  const float* Wls = (const float*)d_in[16];
  const float* bls = (const float*)d_in[17];

  const int N = in_sizes[0] / 3;
  const int E = in_sizes[1] / 2;
  const int* src = ei;
  const int* dst = ei + E;
  float* out = (float*)d_out;

  char* ws = (char*)d_ws;
  size_t o = 0;
  float* dinv = (float*)(ws + o); o += (size_t)N * 4;
  float* qv   = (float*)(ws + o); o += (size_t)N * 4;
  float* bns  = (float*)(ws + o); o += 384 * 4;
  float* W2c  = (float*)(ws + o); o += 4096 * 4;
  float* c2   = (float*)(ws + o); o += 64 * 4;
  float* W3c  = (float*)(ws + o); o += 4096 * 4;
  float* c3   = (float*)(ws + o); o += 64 * 4;
  u16* Bh     = (u16*)(ws + o);   o += (size_t)12 * 2 * 8 * 64 * 8 * 2;
  u16* Bl     = (u16*)(ws + o);   o += (size_t)12 * 2 * 8 * 64 * 8 * 2;
  float* cmu  = (float*)(ws + o); o += 768 * 4;
  float* cls  = (float*)(ws + o); o += 768 * 4;
  u16* Ghi    = (u16*)(ws + o);   o += (size_t)N * 64 * 2;
  u16* Glo    = (u16*)(ws + o);   o += (size_t)N * 64 * 2;
  int* cnt    = (int*)(ws + o);   o += (size_t)N * 4;
  int* rowptr = (int*)(ws + o);   o += ((size_t)N + 1) * 4;
  int* cursor = (int*)(ws + o);   o += (size_t)N * 4;
  int* bsum   = (int*)(ws + o);   o += 64 * 4;
  int* eidx   = (int*)(ws + o);   o += (size_t)E * 4;
  float* B0   = (float*)(ws + o); o += (size_t)N * 64 * 4;
  float* B1   = (float*)(ws + o); o += (size_t)N * 64 * 4;
  // ws_size observed ~1.2 GB; total used ~45 MB.

  const float invN = 1.0f / (float)N;
  int nbN = (N + 255) / 256;
  int nbE = (E + 255) / 256;
  int gb  = (N + 63) / 64;
  int wb  = (N + 3) / 4;
  int sbA = (N + 1023) / 1024;

  // CSR build (edge_index constant across all 4 propagations)
  init_k<<<nbN, 256, 0, stream>>>(cnt, bns, N);
  hist_k<<<nbE, 256, 0, stream>>>(dst, cnt, E);
  scanA<<<sbA, 1024, 0, stream>>>(cnt, rowptr, bsum, N);
  scanB<<<1, 64, 0, stream>>>(bsum, sbA);
  scanC<<<nbN, 256, 0, stream>>>(cnt, rowptr, cursor, bsum, dinv, N, E);
  fill_k<<<nbE, 256, 0, stream>>>(src, dst, cursor, eidx, E);

  // ---- layer 1: fused gather(3ch)+GEMM+stats, writes Z1=B0 and q ----
  l1_fused<<<1024, 256, 0, stream>>>(rowptr, eidx, x, dinv, W1, b1, B0, qv, bns, N);
  prep_small<<<1, 256, 0, stream>>>(bns + 0, g1, be1, W2, W2c, c2, invN);

  // ---- layer 2 (split gather -> GEMM) ----
  gather64<<<wb, 256, 0, stream>>>(rowptr, eidx, B0, B1, N);      // B1 = G1
  gemm_bnq<<<gb, 256, 0, stream>>>(B1, dinv, qv, W2c, c2, b2, B0, bns + 128, N);
  prep_small<<<1, 256, 0, stream>>>(bns + 128, g2, be2, W3, W3c, c3, invN);

  // ---- layer 3 ----
  gather64<<<wb, 256, 0, stream>>>(rowptr, eidx, B0, B1, N);      // B1 = G2
  gemm_bnq<<<gb, 256, 0, stream>>>(B1, dinv, qv, W3c, c3, b3, B0, bns + 256, N);
  prep_head<<<12, 256, 0, stream>>>(bns + 256, g3, be3, Wmu, Wls, Bh, Bl, cmu, cls, invN);

  // ---- final propagate (split-bf16 output) + MFMA head ----
  gather64h<<<wb, 256, 0, stream>>>(rowptr, eidx, B0, Ghi, Glo, N);
  dim3 hgrid(gb, 12);
  head_mfma<<<hgrid, 256, 0, stream>>>(Ghi, Glo, dinv, qv, Bh, Bl,
                                       cmu, bmu, cls, bls, out, N);
}

// Round 14
// 418.794 us; speedup vs baseline: 1.1700x; 1.0210x over previous
//
#include <hip/hip_runtime.h>
#include <cstddef>

// GCN encoder, BN-folded, split gather->GEMM (fusion net-negative, r10/r11).
// Head: split-bf16 MFMA (D = Ah*Bh + Ah*Bl + Al*Bh), weight-stationary:
// each block owns one 128-col chunk, keeps W-frags in registers, streams
// row-tiles (r14). Operands swapped vs r13 so D rows = W-cols -> float4 stores.
// prop(h)[d] = dinv[d]*(P(h)[d] @ W) + b; BN folded via W'=diag(sc)W, c'=sh@W,
// q[d] = sum dinv; epilogue u = dv*acc + dv*q[r]*c'[c] + b[c].

#define NEG_SLOPE 0.01f
#define BN_EPS 1e-5f

typedef unsigned short u16;
typedef __attribute__((ext_vector_type(8))) short bf16x8;
typedef __attribute__((ext_vector_type(4))) float f32x4;

__device__ __forceinline__ unsigned bf16_rne(float x) {
  unsigned u = __float_as_uint(x);
  return (u + 0x7fffu + ((u >> 16) & 1u)) >> 16;
}

__global__ __launch_bounds__(256) void init_k(int* __restrict__ cnt,
                                              float* __restrict__ bns, int N) {
  int i = blockIdx.x * 256 + threadIdx.x;
  if (i < N) cnt[i] = 0;
  if (i < 384) bns[i] = 0.0f;  // 3 layers x {sum[64], sumsq[64]}
}

__global__ __launch_bounds__(256) void hist_k(const int* __restrict__ dst,
                                              int* __restrict__ cnt, int E) {
  int e = blockIdx.x * 256 + threadIdx.x;
  if (e < E) atomicAdd(&cnt[dst[e]], 1);
}

__global__ __launch_bounds__(1024) void scanA(const int* __restrict__ cnt,
                                              int* __restrict__ pre,
                                              int* __restrict__ bsum, int N) {
  __shared__ int sh[1024];
  const int t = threadIdx.x;
  const int i = blockIdx.x * 1024 + t;
  int c = (i < N) ? cnt[i] : 0;
  sh[t] = c;
  __syncthreads();
  for (int off = 1; off < 1024; off <<= 1) {
    int v = (t >= off) ? sh[t - off] : 0;
    __syncthreads();
    sh[t] += v;
    __syncthreads();
  }
  if (i < N) pre[i] = sh[t] - c;  // exclusive
  if (t == 1023) bsum[blockIdx.x] = sh[t];
}

__global__ __launch_bounds__(64) void scanB(int* __restrict__ bsum, int nb) {
  int t = threadIdx.x;
  int orig = (t < nb) ? bsum[t] : 0;
  int v = orig;
#pragma unroll
  for (int off = 1; off < 64; off <<= 1) {
    int u = __shfl_up(v, off);
    if (t >= off) v += u;
  }
  if (t < nb) bsum[t] = v - orig;
}

__global__ __launch_bounds__(256) void scanC(const int* __restrict__ cnt,
                                             int* __restrict__ rowptr,
                                             int* __restrict__ cursor,
                                             const int* __restrict__ bsum,
                                             float* __restrict__ dinv,
                                             int N, int E) {
  int i = blockIdx.x * 256 + threadIdx.x;
  if (i < N) {
    int rp = rowptr[i] + bsum[i >> 10];
    rowptr[i] = rp;
    cursor[i] = rp;
    dinv[i] = rsqrtf((float)(cnt[i] + 1));  // +1 self loop
  }
  if (i == 0) rowptr[N] = E;
}

__global__ __launch_bounds__(256) void fill_k(const int* __restrict__ src,
                                              const int* __restrict__ dst,
                                              int* __restrict__ cursor,
                                              int* __restrict__ eidx, int E) {
  int e = blockIdx.x * 256 + threadIdx.x;
  if (e >= E) return;
  int p = atomicAdd(&cursor[dst[e]], 1);
  eidx[p] = src[e];
}

// Layer 1 fully fused (3ch gather + 3->64 matvec + stats + q).
__global__ __launch_bounds__(256) void l1_fused(
    const int* __restrict__ rowptr, const int* __restrict__ eidx,
    const float* __restrict__ x, const float* __restrict__ dinv,
    const float* __restrict__ W1, const float* __restrict__ b1,
    float* __restrict__ Z, float* __restrict__ q, float* __restrict__ bns, int N) {
  const int t = threadIdx.x, lane = t & 63, wid = t >> 6;
  const int gw = blockIdx.x * 4 + wid;
  const int nw = gridDim.x * 4;
  const float w0 = W1[lane], w1 = W1[64 + lane], w2 = W1[128 + lane];
  const float bb = b1[lane];
  float s1 = 0.f, s2 = 0.f;
  for (int node = gw; node < N; node += nw) {
    int beg = rowptr[node], end = rowptr[node + 1];
    float a0 = 0.f, a1 = 0.f, a2 = 0.f, aq = 0.f;
    for (int e = beg + lane; e < end; e += 64) {
      int s = eidx[e];
      float dv = dinv[s];
      a0 += x[s * 3] * dv;
      a1 += x[s * 3 + 1] * dv;
      a2 += x[s * 3 + 2] * dv;
      aq += dv;
    }
#pragma unroll
    for (int off = 32; off; off >>= 1) {
      a0 += __shfl_xor(a0, off);
      a1 += __shfl_xor(a1, off);
      a2 += __shfl_xor(a2, off);
      aq += __shfl_xor(aq, off);
    }
    float dv = dinv[node];
    a0 += x[node * 3] * dv;
    a1 += x[node * 3 + 1] * dv;
    a2 += x[node * 3 + 2] * dv;
    aq += dv;
    float u = dv * (a0 * w0 + a1 * w1 + a2 * w2) + bb;
    float o = u >= 0.f ? u : NEG_SLOPE * u;
    Z[(size_t)node * 64 + lane] = o * dv;
    s1 += o;
    s2 += o * o;
    if (lane == 0) q[node] = aq;
  }
  __shared__ float red[8][64];
  red[wid][lane] = s1;
  red[4 + wid][lane] = s2;
  __syncthreads();
  if (t < 64) {
    atomicAdd(&bns[t], red[0][t] + red[1][t] + red[2][t] + red[3][t]);
    atomicAdd(&bns[64 + t], red[4][t] + red[5][t] + red[6][t] + red[7][t]);
  }
}

// Standalone gather: G[node][c] = Z[node][c] + sum Z[src][c]; one wave/node.
__global__ __launch_bounds__(256) void gather64(const int* __restrict__ rowptr,
                                                const int* __restrict__ eidx,
                                                const float* __restrict__ Z,
                                                float* __restrict__ G, int N) {
  int node = blockIdx.x * 4 + (threadIdx.x >> 6);
  if (node >= N) return;
  int lane = threadIdx.x & 63;
  int slot = lane >> 4;
  int c4 = (lane & 15) << 2;
  int beg = rowptr[node], end = rowptr[node + 1];
  float ax = 0.f, ay = 0.f, az = 0.f, aw = 0.f;
  int e = beg + slot;
  for (; e + 4 < end; e += 8) {
    int s0 = eidx[e], s1 = eidx[e + 4];
    float4 v0 = *(const float4*)(Z + (size_t)s0 * 64 + c4);
    float4 v1 = *(const float4*)(Z + (size_t)s1 * 64 + c4);
    ax += v0.x + v1.x;
    ay += v0.y + v1.y;
    az += v0.z + v1.z;
    aw += v0.w + v1.w;
  }
  if (e < end) {
    int s0 = eidx[e];
    float4 v0 = *(const float4*)(Z + (size_t)s0 * 64 + c4);
    ax += v0.x; ay += v0.y; az += v0.z; aw += v0.w;
  }
#pragma unroll
  for (int off = 16; off < 64; off <<= 1) {
    ax += __shfl_xor(ax, off);
    ay += __shfl_xor(ay, off);
    az += __shfl_xor(az, off);
    aw += __shfl_xor(aw, off);
  }
  if (slot == 0) {
    float4 self = *(const float4*)(Z + (size_t)node * 64 + c4);
    float4 o = make_float4(ax + self.x, ay + self.y, az + self.z, aw + self.w);
    *(float4*)(G + (size_t)node * 64 + c4) = o;
  }
}

// Final gather: writes packed split-bf16 (hi/lo) for the MFMA head.
__global__ __launch_bounds__(256) void gather64h(const int* __restrict__ rowptr,
                                                 const int* __restrict__ eidx,
                                                 const float* __restrict__ Z,
                                                 u16* __restrict__ Ghi,
                                                 u16* __restrict__ Glo, int N) {
  int node = blockIdx.x * 4 + (threadIdx.x >> 6);
  if (node >= N) return;
  int lane = threadIdx.x & 63;
  int slot = lane >> 4;
  int c4 = (lane & 15) << 2;
  int beg = rowptr[node], end = rowptr[node + 1];
  float ax = 0.f, ay = 0.f, az = 0.f, aw = 0.f;
  int e = beg + slot;
  for (; e + 4 < end; e += 8) {
    int s0 = eidx[e], s1 = eidx[e + 4];
    float4 v0 = *(const float4*)(Z + (size_t)s0 * 64 + c4);
    float4 v1 = *(const float4*)(Z + (size_t)s1 * 64 + c4);
    ax += v0.x + v1.x;
    ay += v0.y + v1.y;
    az += v0.z + v1.z;
    aw += v0.w + v1.w;
  }
  if (e < end) {
    int s0 = eidx[e];
    float4 v0 = *(const float4*)(Z + (size_t)s0 * 64 + c4);
    ax += v0.x; ay += v0.y; az += v0.z; aw += v0.w;
  }
#pragma unroll
  for (int off = 16; off < 64; off <<= 1) {
    ax += __shfl_xor(ax, off);
    ay += __shfl_xor(ay, off);
    az += __shfl_xor(az, off);
    aw += __shfl_xor(aw, off);
  }
  if (slot == 0) {
    float4 self = *(const float4*)(Z + (size_t)node * 64 + c4);
    float o0 = ax + self.x, o1 = ay + self.y, o2 = az + self.z, o3 = aw + self.w;
    unsigned h0 = bf16_rne(o0), h1 = bf16_rne(o1), h2 = bf16_rne(o2), h3 = bf16_rne(o3);
    unsigned l0 = bf16_rne(o0 - __uint_as_float(h0 << 16));
    unsigned l1 = bf16_rne(o1 - __uint_as_float(h1 << 16));
    unsigned l2 = bf16_rne(o2 - __uint_as_float(h2 << 16));
    unsigned l3 = bf16_rne(o3 - __uint_as_float(h3 << 16));
    uint2 hv = make_uint2(h0 | (h1 << 16), h2 | (h3 << 16));
    uint2 lv = make_uint2(l0 | (l1 << 16), l2 | (l3 << 16));
    *(uint2*)(Ghi + (size_t)node * 64 + c4) = hv;
    *(uint2*)(Glo + (size_t)node * 64 + c4) = lv;
  }
}

// sc/sh from bns, then W'[k][c] = sc[k]*W[k][c] (64x64), c'[c] = sum_k sh[k]*W[k][c].
__global__ __launch_bounds__(256) void prep_small(
    const float* __restrict__ bns, const float* __restrict__ g,
    const float* __restrict__ be, const float* __restrict__ W,
    float* __restrict__ Wc, float* __restrict__ cx, float invN) {
  __shared__ float sc[64], sh[64], part[4][64];
  int t = threadIdx.x;
  if (t < 64) {
    float mean = bns[t] * invN;
    float var = bns[64 + t] * invN - mean * mean;
    float s = g[t] * rsqrtf(var + BN_EPS);
    sc[t] = s;
    sh[t] = be[t] - mean * s;
  }
  __syncthreads();
  int c = t & 63, kq = t >> 6;
  float p = 0.f;
  for (int k = kq * 16; k < kq * 16 + 16; ++k) {
    float w = W[k * 64 + c];
    Wc[k * 64 + c] = sc[k] * w;
    p += sh[k] * w;
  }
  part[kq][c] = p;
  __syncthreads();
  if (t < 64) cx[t] = part[0][t] + part[1][t] + part[2][t] + part[3][t];
}

// Head weight prep: cx = sh@W, W' = sc[k]*W packed split-bf16 in fragment
// order (lane = ((k>>3)&3)*16 + col%16, j = k&7) — valid as the MFMA
// A-operand (row=l&15=col index, k=(l>>4)*8+j).
// Bh/Bl index: [(head*6+cc)][p=k>>5][ct][lane][j]. grid.x=12.
__global__ __launch_bounds__(256) void prep_head(
    const float* __restrict__ bns, const float* __restrict__ g,
    const float* __restrict__ be, const float* __restrict__ Wmu,
    const float* __restrict__ Wls, u16* __restrict__ Bh, u16* __restrict__ Bl,
    float* __restrict__ cmu, float* __restrict__ cls, float invN) {
  __shared__ float sc[64], sh[64], part[2][128];
  int t = threadIdx.x;
  if (t < 64) {
    float mean = bns[t] * invN;
    float var = bns[64 + t] * invN - mean * mean;
    float s = g[t] * rsqrtf(var + BN_EPS);
    sc[t] = s;
    sh[t] = be[t] - mean * s;
  }
  __syncthreads();
  int blk = blockIdx.x;
  int head = blk >= 6 ? 1 : 0;
  int cc = head ? blk - 6 : blk;
  int c0 = cc * 128;
  const float* W = head ? Wls : Wmu;
  float* cx = head ? cls : cmu;
  int cl = t & 127, kh = t >> 7;
  int c = c0 + cl;
  int ct = cl >> 4, jc = cl & 15;
  size_t base = (size_t)(head * 6 + cc) * 2 * 8 * 64 * 8;
  float p = 0.f;
  for (int k = kh * 32; k < kh * 32 + 32; ++k) {
    float w = W[(size_t)k * 768 + c];
    float wc = sc[k] * w;
    p += sh[k] * w;
    unsigned hi = bf16_rne(wc);
    unsigned lo = bf16_rne(wc - __uint_as_float(hi << 16));
    int lane = ((k >> 3) & 3) * 16 + jc;
    size_t idx = base + (((size_t)kh * 8 + ct) * 64 + lane) * 8 + (k & 7);
    Bh[idx] = (u16)hi;
    Bl[idx] = (u16)lo;
  }
  part[kh][cl] = p;
  __syncthreads();
  if (t < 128) cx[c0 + t] = part[0][t] + part[1][t];
}

// Layers 2/3 GEMM (split from gather), 64x64 tile, 4x4/thread, fp32.
__global__ __launch_bounds__(256, 4) void gemm_bnq(
    const float* __restrict__ G, const float* __restrict__ dinv,
    const float* __restrict__ q, const float* __restrict__ Wc,
    const float* __restrict__ cx, const float* __restrict__ b,
    float* __restrict__ Z, float* __restrict__ bns, int N) {
  __shared__ __align__(16) float P[64][68];
  __shared__ __align__(16) float Ws[64][64];
  const int t = threadIdx.x;
  const int r0 = blockIdx.x * 64;

  for (int i = t; i < 1024; i += 256) {
    int r = i >> 4, k4 = (i & 15) << 2, gr = r0 + r;
    float4 v = make_float4(0.f, 0.f, 0.f, 0.f);
    if (gr < N) v = *(const float4*)(G + (size_t)gr * 64 + k4);
    *(float4*)&P[r][k4] = v;
  }
  for (int i = t; i < 4096; i += 256) Ws[i >> 6][i & 63] = Wc[i];
  __syncthreads();

  const int tr = t >> 4, tc4 = (t & 15) << 2;
  float acc[4][4] = {};
#pragma unroll 8
  for (int k = 0; k < 64; ++k) {
    float4 w = *(const float4*)&Ws[k][tc4];
#pragma unroll
    for (int i = 0; i < 4; ++i) {
      float a = P[tr + 16 * i][k];
      acc[i][0] += a * w.x;
      acc[i][1] += a * w.y;
      acc[i][2] += a * w.z;
      acc[i][3] += a * w.w;
    }
  }

  float s1[4] = {0.f, 0.f, 0.f, 0.f}, s2[4] = {0.f, 0.f, 0.f, 0.f};
  float4 bb = *(const float4*)(b + tc4);
  float4 cc = *(const float4*)(cx + tc4);
#pragma unroll
  for (int i = 0; i < 4; ++i) {
    int r = r0 + tr + 16 * i;
    if (r < N) {
      float dv = dinv[r];
      float dq = dv * q[r];
      float u0 = acc[i][0] * dv + dq * cc.x + bb.x;
      float u1 = acc[i][1] * dv + dq * cc.y + bb.y;
      float u2 = acc[i][2] * dv + dq * cc.z + bb.z;
      float u3 = acc[i][3] * dv + dq * cc.w + bb.w;
      float o0 = u0 >= 0.f ? u0 : NEG_SLOPE * u0;
      float o1 = u1 >= 0.f ? u1 : NEG_SLOPE * u1;
      float o2 = u2 >= 0.f ? u2 : NEG_SLOPE * u2;
      float o3 = u3 >= 0.f ? u3 : NEG_SLOPE * u3;
      float4 z = make_float4(o0 * dv, o1 * dv, o2 * dv, o3 * dv);
      *(float4*)(Z + (size_t)r * 64 + tc4) = z;
      s1[0] += o0; s2[0] += o0 * o0;
      s1[1] += o1; s2[1] += o1 * o1;
      s1[2] += o2; s2[2] += o2 * o2;
      s1[3] += o3; s2[3] += o3 * o3;
    }
  }
  __syncthreads();  // Ws no longer needed; reuse for BN reduction
  float (*red1)[64] = (float(*)[64]) & Ws[0][0];
  float (*red2)[64] = (float(*)[64]) & Ws[16][0];
#pragma unroll
  for (int j = 0; j < 4; ++j) {
    red1[tr][tc4 + j] = s1[j];
    red2[tr][tc4 + j] = s2[j];
  }
  __syncthreads();
  if (t < 64) {
    float a1 = 0.f, a2 = 0.f;
#pragma unroll
    for (int i = 0; i < 16; ++i) {
      a1 += red1[i][t];
      a2 += red2[i][t];
    }
    atomicAdd(&bns[t], a1);
    atomicAdd(&bns[64 + t], a2);
  }
}

// Weight-stationary MFMA head. Grid (64, 12): block owns one 128-col chunk
// (y: 0-5 mu, 6-11 ls), loads its 32 W-frags once (A operand), strides over
// 64-row tiles (wave = 16 rows). mfma(W, G) -> D[wcol][grow]: lane holds
// 4 consecutive cols of ONE row -> float4 stores. No LDS, no barriers.
__global__ __launch_bounds__(256) void head_mfma2(
    const u16* __restrict__ Ghi, const u16* __restrict__ Glo,
    const float* __restrict__ dinv, const float* __restrict__ q,
    const u16* __restrict__ Bh, const u16* __restrict__ Bl,
    const float* __restrict__ cmu, const float* __restrict__ bmu,
    const float* __restrict__ cls, const float* __restrict__ bls,
    float* __restrict__ OUT, int N, int ntiles) {
  const int t = threadIdx.x;
  const int w = t >> 6, l = t & 63;
  const int yy = blockIdx.y;
  const int head = (yy >= 6) ? 1 : 0;
  const int cc = head ? yy - 6 : yy;
  const int c0 = cc * 128;
  const float* cx = head ? cls : cmu;
  const float* bb = head ? bls : bmu;
  float* O = OUT + (head ? (size_t)N * 768 : 0);

  // W fragments, loaded once per block: [ct][khalf], hi and lo.
  const size_t base = (size_t)(head * 6 + cc) * 2 * 8 * 64 * 8;
  const u16* bhp = Bh + base;
  const u16* blp = Bl + base;
  bf16x8 wh[8][2], wl[8][2];
#pragma unroll
  for (int ct = 0; ct < 8; ++ct) {
    wh[ct][0] = *(const bf16x8*)(bhp + (((size_t)ct) * 64 + l) * 8);
    wh[ct][1] = *(const bf16x8*)(bhp + (((size_t)(8 + ct)) * 64 + l) * 8);
    wl[ct][0] = *(const bf16x8*)(blp + (((size_t)ct) * 64 + l) * 8);
    wl[ct][1] = *(const bf16x8*)(blp + (((size_t)(8 + ct)) * 64 + l) * 8);
  }

  const int colb = c0 + ((l >> 4) << 2);
  for (int tile = blockIdx.x; tile < ntiles; tile += gridDim.x) {
    const int grow = tile * 64 + w * 16 + (l & 15);
    const int gc = grow < N ? grow : N - 1;
    const u16* gh = Ghi + (size_t)gc * 64 + ((l >> 4) << 3);
    const u16* gl = Glo + (size_t)gc * 64 + ((l >> 4) << 3);
    const bf16x8 gh0 = *(const bf16x8*)gh;
    const bf16x8 gh1 = *(const bf16x8*)(gh + 32);
    const bf16x8 gl0 = *(const bf16x8*)gl;
    const bf16x8 gl1 = *(const bf16x8*)(gl + 32);
    const float dv = dinv[gc];
    const float dq = dv * q[gc];

#pragma unroll
    for (int ct = 0; ct < 8; ++ct) {
      f32x4 a = {0.f, 0.f, 0.f, 0.f};
      a = __builtin_amdgcn_mfma_f32_16x16x32_bf16(wh[ct][0], gh0, a, 0, 0, 0);
      a = __builtin_amdgcn_mfma_f32_16x16x32_bf16(wh[ct][1], gh1, a, 0, 0, 0);
      a = __builtin_amdgcn_mfma_f32_16x16x32_bf16(wl[ct][0], gh0, a, 0, 0, 0);
      a = __builtin_amdgcn_mfma_f32_16x16x32_bf16(wl[ct][1], gh1, a, 0, 0, 0);
      a = __builtin_amdgcn_mfma_f32_16x16x32_bf16(wh[ct][0], gl0, a, 0, 0, 0);
      a = __builtin_amdgcn_mfma_f32_16x16x32_bf16(wh[ct][1], gl1, a, 0, 0, 0);
      if (grow < N) {
        int col = colb + ct * 16;
        float4 cxv = *(const float4*)(cx + col);
        float4 bbv = *(const float4*)(bb + col);
        float4 o = make_float4(a[0] * dv + dq * cxv.x + bbv.x,
                               a[1] * dv + dq * cxv.y + bbv.y,
                               a[2] * dv + dq * cxv.z + bbv.z,
                               a[3] * dv + dq * cxv.w + bbv.w);
        *(float4*)(O + (size_t)grow * 768 + col) = o;
      }
    }
  }
}

extern "C" void kernel_launch(void* const* d_in, const int* in_sizes, int n_in,
                              void* d_out, int out_size, void* d_ws, size_t ws_size,
                              hipStream_t stream) {
  const float* x   = (const float*)d_in[0];
  const int*   ei  = (const int*)d_in[1];
  const float* W1  = (const float*)d_in[2];
  const float* b1  = (const float*)d_in[3];
  const float* g1  = (const float*)d_in[4];
  const float* be1 = (const float*)d_in[5];
  const float* W2  = (const float*)d_in[6];
  const float* b2  = (const float*)d_in[7];
  const float* g2  = (const float*)d_in[8];
  const float* be2 = (const float*)d_in[9];
  const float* W3  = (const float*)d_in[10];
  const float* b3  = (const float*)d_in[11];
  const float* g3  = (const float*)d_in[12];
  const float* be3 = (const float*)d_in[13];
  const float* Wmu = (const float*)d_in[14];
  const float* bmu = (const float*)d_in[15];
  const float* Wls = (const float*)d_in[16];
  const float* bls = (const float*)d_in[17];

  const int N = in_sizes[0] / 3;
  const int E = in_sizes[1] / 2;
  const int* src = ei;
  const int* dst = ei + E;
  float* out = (float*)d_out;

  char* ws = (char*)d_ws;
  size_t o = 0;
  float* dinv = (float*)(ws + o); o += (size_t)N * 4;
  float* qv   = (float*)(ws + o); o += (size_t)N * 4;
  float* bns  = (float*)(ws + o); o += 384 * 4;
  float* W2c  = (float*)(ws + o); o += 4096 * 4;
  float* c2   = (float*)(ws + o); o += 64 * 4;
  float* W3c  = (float*)(ws + o); o += 4096 * 4;
  float* c3   = (float*)(ws + o); o += 64 * 4;
  u16* Bh     = (u16*)(ws + o);   o += (size_t)12 * 2 * 8 * 64 * 8 * 2;
  u16* Bl     = (u16*)(ws + o);   o += (size_t)12 * 2 * 8 * 64 * 8 * 2;
  float* cmu  = (float*)(ws + o); o += 768 * 4;
  float* cls  = (float*)(ws + o); o += 768 * 4;
  u16* Ghi    = (u16*)(ws + o);   o += (size_t)N * 64 * 2;
  u16* Glo    = (u16*)(ws + o);   o += (size_t)N * 64 * 2;
  int* cnt    = (int*)(ws + o);   o += (size_t)N * 4;
  int* rowptr = (int*)(ws + o);   o += ((size_t)N + 1) * 4;
  int* cursor = (int*)(ws + o);   o += (size_t)N * 4;
  int* bsum   = (int*)(ws + o);   o += 64 * 4;
  int* eidx   = (int*)(ws + o);   o += (size_t)E * 4;
  float* B0   = (float*)(ws + o); o += (size_t)N * 64 * 4;
  float* B1   = (float*)(ws + o); o += (size_t)N * 64 * 4;
  // ws_size observed ~1.2 GB; total used ~45 MB.

  const float invN = 1.0f / (float)N;
  int nbN = (N + 255) / 256;
  int nbE = (E + 255) / 256;
  int gb  = (N + 63) / 64;
  int wb  = (N + 3) / 4;
  int sbA = (N + 1023) / 1024;

  // CSR build (edge_index constant across all 4 propagations)
  init_k<<<nbN, 256, 0, stream>>>(cnt, bns, N);
  hist_k<<<nbE, 256, 0, stream>>>(dst, cnt, E);
  scanA<<<sbA, 1024, 0, stream>>>(cnt, rowptr, bsum, N);
  scanB<<<1, 64, 0, stream>>>(bsum, sbA);
  scanC<<<nbN, 256, 0, stream>>>(cnt, rowptr, cursor, bsum, dinv, N, E);
  fill_k<<<nbE, 256, 0, stream>>>(src, dst, cursor, eidx, E);

  // ---- layer 1: fused gather(3ch)+GEMM+stats, writes Z1=B0 and q ----
  l1_fused<<<1024, 256, 0, stream>>>(rowptr, eidx, x, dinv, W1, b1, B0, qv, bns, N);
  prep_small<<<1, 256, 0, stream>>>(bns + 0, g1, be1, W2, W2c, c2, invN);

  // ---- layer 2 (split gather -> GEMM) ----
  gather64<<<wb, 256, 0, stream>>>(rowptr, eidx, B0, B1, N);      // B1 = G1
  gemm_bnq<<<gb, 256, 0, stream>>>(B1, dinv, qv, W2c, c2, b2, B0, bns + 128, N);
  prep_small<<<1, 256, 0, stream>>>(bns + 128, g2, be2, W3, W3c, c3, invN);

  // ---- layer 3 ----
  gather64<<<wb, 256, 0, stream>>>(rowptr, eidx, B0, B1, N);      // B1 = G2
  gemm_bnq<<<gb, 256, 0, stream>>>(B1, dinv, qv, W3c, c3, b3, B0, bns + 256, N);
  prep_head<<<12, 256, 0, stream>>>(bns + 256, g3, be3, Wmu, Wls, Bh, Bl, cmu, cls, invN);

  // ---- final propagate (split-bf16 output) + weight-stationary MFMA head ----
  gather64h<<<wb, 256, 0, stream>>>(rowptr, eidx, B0, Ghi, Glo, N);
  dim3 hgrid(64, 12);
  head_mfma2<<<hgrid, 256, 0, stream>>>(Ghi, Glo, dinv, qv, Bh, Bl,
                                        cmu, bmu, cls, bls, out, N, gb);
}

// Round 15
// 417.941 us; speedup vs baseline: 1.1724x; 1.0020x over previous
//
#include <hip/hip_runtime.h>
#include <cstddef>

// GCN encoder, BN-folded, split gather->GEMM (fusion net-negative r10/r11).
// Head: weight-stationary split-bf16 MFMA (r14). r15: prep_small folded into
// the layer GEMMs (sc/sh/cx computed in-block from raw W + bns), and scanC
// packs xd[node]={x*dinv, dinv} so l1 does one float4 per edge.
// prop(h)[d] = dinv[d]*(P(h)[d] @ W) + b; BN folded via W'=diag(sc)W, c'=sh@W,
// q[d] = sum dinv; epilogue u = dv*acc + dv*q[r]*c'[c] + b[c].

#define NEG_SLOPE 0.01f
#define BN_EPS 1e-5f

typedef unsigned short u16;
typedef __attribute__((ext_vector_type(8))) short bf16x8;
typedef __attribute__((ext_vector_type(4))) float f32x4;

__device__ __forceinline__ unsigned bf16_rne(float x) {
  unsigned u = __float_as_uint(x);
  return (u + 0x7fffu + ((u >> 16) & 1u)) >> 16;
}

__global__ __launch_bounds__(256) void init_k(int* __restrict__ cnt,
                                              float* __restrict__ bns, int N) {
  int i = blockIdx.x * 256 + threadIdx.x;
  if (i < N) cnt[i] = 0;
  if (i < 384) bns[i] = 0.0f;  // 3 layers x {sum[64], sumsq[64]}
}

__global__ __launch_bounds__(256) void hist_k(const int* __restrict__ dst,
                                              int* __restrict__ cnt, int E) {
  int e = blockIdx.x * 256 + threadIdx.x;
  if (e < E) atomicAdd(&cnt[dst[e]], 1);
}

__global__ __launch_bounds__(1024) void scanA(const int* __restrict__ cnt,
                                              int* __restrict__ pre,
                                              int* __restrict__ bsum, int N) {
  __shared__ int sh[1024];
  const int t = threadIdx.x;
  const int i = blockIdx.x * 1024 + t;
  int c = (i < N) ? cnt[i] : 0;
  sh[t] = c;
  __syncthreads();
  for (int off = 1; off < 1024; off <<= 1) {
    int v = (t >= off) ? sh[t - off] : 0;
    __syncthreads();
    sh[t] += v;
    __syncthreads();
  }
  if (i < N) pre[i] = sh[t] - c;  // exclusive
  if (t == 1023) bsum[blockIdx.x] = sh[t];
}

__global__ __launch_bounds__(64) void scanB(int* __restrict__ bsum, int nb) {
  int t = threadIdx.x;
  int orig = (t < nb) ? bsum[t] : 0;
  int v = orig;
#pragma unroll
  for (int off = 1; off < 64; off <<= 1) {
    int u = __shfl_up(v, off);
    if (t >= off) v += u;
  }
  if (t < nb) bsum[t] = v - orig;
}

// Phase C: rowptr/cursor finalize, dinv, and xd = {x*dinv, dinv} pack.
__global__ __launch_bounds__(256) void scanC(const int* __restrict__ cnt,
                                             int* __restrict__ rowptr,
                                             int* __restrict__ cursor,
                                             const int* __restrict__ bsum,
                                             const float* __restrict__ x,
                                             float* __restrict__ dinv,
                                             float4* __restrict__ xd,
                                             int N, int E) {
  int i = blockIdx.x * 256 + threadIdx.x;
  if (i < N) {
    int rp = rowptr[i] + bsum[i >> 10];
    rowptr[i] = rp;
    cursor[i] = rp;
    float dv = rsqrtf((float)(cnt[i] + 1));  // +1 self loop
    dinv[i] = dv;
    xd[i] = make_float4(x[i * 3] * dv, x[i * 3 + 1] * dv, x[i * 3 + 2] * dv, dv);
  }
  if (i == 0) rowptr[N] = E;
}

__global__ __launch_bounds__(256) void fill_k(const int* __restrict__ src,
                                              const int* __restrict__ dst,
                                              int* __restrict__ cursor,
                                              int* __restrict__ eidx, int E) {
  int e = blockIdx.x * 256 + threadIdx.x;
  if (e >= E) return;
  int p = atomicAdd(&cursor[dst[e]], 1);
  eidx[p] = src[e];
}

// Layer 1 fully fused (3ch gather via xd float4 + 3->64 matvec + stats + q).
__global__ __launch_bounds__(256) void l1_fused(
    const int* __restrict__ rowptr, const int* __restrict__ eidx,
    const float4* __restrict__ xd, const float* __restrict__ W1,
    const float* __restrict__ b1, float* __restrict__ Z, float* __restrict__ q,
    float* __restrict__ bns, int N) {
  const int t = threadIdx.x, lane = t & 63, wid = t >> 6;
  const int gw = blockIdx.x * 4 + wid;
  const int nw = gridDim.x * 4;
  const float w0 = W1[lane], w1 = W1[64 + lane], w2 = W1[128 + lane];
  const float bb = b1[lane];
  float s1 = 0.f, s2 = 0.f;
  for (int node = gw; node < N; node += nw) {
    int beg = rowptr[node], end = rowptr[node + 1];
    float a0 = 0.f, a1 = 0.f, a2 = 0.f, aq = 0.f;
    for (int e = beg + lane; e < end; e += 64) {
      float4 v = xd[eidx[e]];
      a0 += v.x;
      a1 += v.y;
      a2 += v.z;
      aq += v.w;
    }
#pragma unroll
    for (int off = 32; off; off >>= 1) {
      a0 += __shfl_xor(a0, off);
      a1 += __shfl_xor(a1, off);
      a2 += __shfl_xor(a2, off);
      aq += __shfl_xor(aq, off);
    }
    float4 sv = xd[node];
    float dv = sv.w;
    a0 += sv.x;
    a1 += sv.y;
    a2 += sv.z;
    aq += dv;
    float u = dv * (a0 * w0 + a1 * w1 + a2 * w2) + bb;
    float o = u >= 0.f ? u : NEG_SLOPE * u;
    Z[(size_t)node * 64 + lane] = o * dv;
    s1 += o;
    s2 += o * o;
    if (lane == 0) q[node] = aq;
  }
  __shared__ float red[8][64];
  red[wid][lane] = s1;
  red[4 + wid][lane] = s2;
  __syncthreads();
  if (t < 64) {
    atomicAdd(&bns[t], red[0][t] + red[1][t] + red[2][t] + red[3][t]);
    atomicAdd(&bns[64 + t], red[4][t] + red[5][t] + red[6][t] + red[7][t]);
  }
}

// Standalone gather: G[node][c] = Z[node][c] + sum Z[src][c]; one wave/node.
__global__ __launch_bounds__(256) void gather64(const int* __restrict__ rowptr,
                                                const int* __restrict__ eidx,
                                                const float* __restrict__ Z,
                                                float* __restrict__ G, int N) {
  int node = blockIdx.x * 4 + (threadIdx.x >> 6);
  if (node >= N) return;
  int lane = threadIdx.x & 63;
  int slot = lane >> 4;
  int c4 = (lane & 15) << 2;
  int beg = rowptr[node], end = rowptr[node + 1];
  float ax = 0.f, ay = 0.f, az = 0.f, aw = 0.f;
  int e = beg + slot;
  for (; e + 4 < end; e += 8) {
    int s0 = eidx[e], s1 = eidx[e + 4];
    float4 v0 = *(const float4*)(Z + (size_t)s0 * 64 + c4);
    float4 v1 = *(const float4*)(Z + (size_t)s1 * 64 + c4);
    ax += v0.x + v1.x;
    ay += v0.y + v1.y;
    az += v0.z + v1.z;
    aw += v0.w + v1.w;
  }
  if (e < end) {
    int s0 = eidx[e];
    float4 v0 = *(const float4*)(Z + (size_t)s0 * 64 + c4);
    ax += v0.x; ay += v0.y; az += v0.z; aw += v0.w;
  }
#pragma unroll
  for (int off = 16; off < 64; off <<= 1) {
    ax += __shfl_xor(ax, off);
    ay += __shfl_xor(ay, off);
    az += __shfl_xor(az, off);
    aw += __shfl_xor(aw, off);
  }
  if (slot == 0) {
    float4 self = *(const float4*)(Z + (size_t)node * 64 + c4);
    float4 o = make_float4(ax + self.x, ay + self.y, az + self.z, aw + self.w);
    *(float4*)(G + (size_t)node * 64 + c4) = o;
  }
}

// Final gather: writes packed split-bf16 (hi/lo) for the MFMA head.
__global__ __launch_bounds__(256) void gather64h(const int* __restrict__ rowptr,
                                                 const int* __restrict__ eidx,
                                                 const float* __restrict__ Z,
                                                 u16* __restrict__ Ghi,
                                                 u16* __restrict__ Glo, int N) {
  int node = blockIdx.x * 4 + (threadIdx.x >> 6);
  if (node >= N) return;
  int lane = threadIdx.x & 63;
  int slot = lane >> 4;
  int c4 = (lane & 15) << 2;
  int beg = rowptr[node], end = rowptr[node + 1];
  float ax = 0.f, ay = 0.f, az = 0.f, aw = 0.f;
  int e = beg + slot;
  for (; e + 4 < end; e += 8) {
    int s0 = eidx[e], s1 = eidx[e + 4];
    float4 v0 = *(const float4*)(Z + (size_t)s0 * 64 + c4);
    float4 v1 = *(const float4*)(Z + (size_t)s1 * 64 + c4);
    ax += v0.x + v1.x;
    ay += v0.y + v1.y;
    az += v0.z + v1.z;
    aw += v0.w + v1.w;
  }
  if (e < end) {
    int s0 = eidx[e];
    float4 v0 = *(const float4*)(Z + (size_t)s0 * 64 + c4);
    ax += v0.x; ay += v0.y; az += v0.z; aw += v0.w;
  }
#pragma unroll
  for (int off = 16; off < 64; off <<= 1) {
    ax += __shfl_xor(ax, off);
    ay += __shfl_xor(ay, off);
    az += __shfl_xor(az, off);
    aw += __shfl_xor(aw, off);
  }
  if (slot == 0) {
    float4 self = *(const float4*)(Z + (size_t)node * 64 + c4);
    float o0 = ax + self.x, o1 = ay + self.y, o2 = az + self.z, o3 = aw + self.w;
    unsigned h0 = bf16_rne(o0), h1 = bf16_rne(o1), h2 = bf16_rne(o2), h3 = bf16_rne(o3);
    unsigned l0 = bf16_rne(o0 - __uint_as_float(h0 << 16));
    unsigned l1 = bf16_rne(o1 - __uint_as_float(h1 << 16));
    unsigned l2 = bf16_rne(o2 - __uint_as_float(h2 << 16));
    unsigned l3 = bf16_rne(o3 - __uint_as_float(h3 << 16));
    uint2 hv = make_uint2(h0 | (h1 << 16), h2 | (h3 << 16));
    uint2 lv = make_uint2(l0 | (l1 << 16), l2 | (l3 << 16));
    *(uint2*)(Ghi + (size_t)node * 64 + c4) = hv;
    *(uint2*)(Glo + (size_t)node * 64 + c4) = lv;
  }
}

// Head weight prep: cx = sh@W, W' = sc[k]*W packed split-bf16 in fragment
// order (lane = ((k>>3)&3)*16 + col%16, j = k&7).
// Bh/Bl index: [(head*6+cc)][p=k>>5][ct][lane][j]. grid.x=12.
__global__ __launch_bounds__(256) void prep_head(
    const float* __restrict__ bns, const float* __restrict__ g,
    const float* __restrict__ be, const float* __restrict__ Wmu,
    const float* __restrict__ Wls, u16* __restrict__ Bh, u16* __restrict__ Bl,
    float* __restrict__ cmu, float* __restrict__ cls, float invN) {
  __shared__ float sc[64], sh[64], part[2][128];
  int t = threadIdx.x;
  if (t < 64) {
    float mean = bns[t] * invN;
    float var = bns[64 + t] * invN - mean * mean;
    float s = g[t] * rsqrtf(var + BN_EPS);
    sc[t] = s;
    sh[t] = be[t] - mean * s;
  }
  __syncthreads();
  int blk = blockIdx.x;
  int head = blk >= 6 ? 1 : 0;
  int cc = head ? blk - 6 : blk;
  int c0 = cc * 128;
  const float* W = head ? Wls : Wmu;
  float* cx = head ? cls : cmu;
  int cl = t & 127, kh = t >> 7;
  int c = c0 + cl;
  int ct = cl >> 4, jc = cl & 15;
  size_t base = (size_t)(head * 6 + cc) * 2 * 8 * 64 * 8;
  float p = 0.f;
  for (int k = kh * 32; k < kh * 32 + 32; ++k) {
    float w = W[(size_t)k * 768 + c];
    float wc = sc[k] * w;
    p += sh[k] * w;
    unsigned hi = bf16_rne(wc);
    unsigned lo = bf16_rne(wc - __uint_as_float(hi << 16));
    int lane = ((k >> 3) & 3) * 16 + jc;
    size_t idx = base + (((size_t)kh * 8 + ct) * 64 + lane) * 8 + (k & 7);
    Bh[idx] = (u16)hi;
    Bl[idx] = (u16)lo;
  }
  part[kh][cl] = p;
  __syncthreads();
  if (t < 128) cx[c0 + t] = part[0][t] + part[1][t];
}

// Layers 2/3 GEMM with integrated BN-weight prep: block computes sc/sh from
// prev-layer bns, stages raw W and scales in LDS, computes cx = sh@W.
// Z_next = LeakyReLU(dv*(G @ W') + dv*q[r]*cx + b) * dv, plus BN stats of o.
__global__ __launch_bounds__(256, 4) void gemm_bnq2(
    const float* __restrict__ G, const float* __restrict__ dinv,
    const float* __restrict__ q, const float* __restrict__ W,
    const float* __restrict__ g, const float* __restrict__ be,
    const float* __restrict__ bnsPrev, const float* __restrict__ b,
    float* __restrict__ Z, float* __restrict__ bnsOut, float invN, int N) {
  __shared__ __align__(16) float P[64][68];
  __shared__ __align__(16) float Ws[64][64];
  __shared__ float scl[64], shl[64], cxl[64], part[4][64];
  const int t = threadIdx.x;
  const int r0 = blockIdx.x * 64;

  if (t < 64) {
    float mean = bnsPrev[t] * invN;
    float var = bnsPrev[64 + t] * invN - mean * mean;
    float s = g[t] * rsqrtf(var + BN_EPS);
    scl[t] = s;
    shl[t] = be[t] - mean * s;
  }
  for (int i = t; i < 1024; i += 256) {
    int r = i >> 4, k4 = (i & 15) << 2, gr = r0 + r;
    float4 v = make_float4(0.f, 0.f, 0.f, 0.f);
    if (gr < N) v = *(const float4*)(G + (size_t)gr * 64 + k4);
    *(float4*)&P[r][k4] = v;
  }
  for (int i = t; i < 4096; i += 256) Ws[i >> 6][i & 63] = W[i];
  __syncthreads();

  {  // scale Ws by sc[k] and accumulate cx partials (thread t: c = t&63 fixed)
    const int c = t & 63, k0 = t >> 6;
    float p = 0.f;
#pragma unroll
    for (int s = 0; s < 16; ++s) {
      int k = k0 + (s << 2);
      float w = Ws[k][c];
      Ws[k][c] = scl[k] * w;
      p += shl[k] * w;
    }
    part[k0][c] = p;
  }
  __syncthreads();
  if (t < 64) cxl[t] = part[0][t] + part[1][t] + part[2][t] + part[3][t];
  __syncthreads();

  const int tr = t >> 4, tc4 = (t & 15) << 2;
  float acc[4][4] = {};
#pragma unroll 8
  for (int k = 0; k < 64; ++k) {
    float4 w = *(const float4*)&Ws[k][tc4];
#pragma unroll
    for (int i = 0; i < 4; ++i) {
      float a = P[tr + 16 * i][k];
      acc[i][0] += a * w.x;
      acc[i][1] += a * w.y;
      acc[i][2] += a * w.z;
      acc[i][3] += a * w.w;
    }
  }

  float s1[4] = {0.f, 0.f, 0.f, 0.f}, s2[4] = {0.f, 0.f, 0.f, 0.f};
  float4 bb = *(const float4*)(b + tc4);
  float4 cc = make_float4(cxl[tc4], cxl[tc4 + 1], cxl[tc4 + 2], cxl[tc4 + 3]);
#pragma unroll
  for (int i = 0; i < 4; ++i) {
    int r = r0 + tr + 16 * i;
    if (r < N) {
      float dv = dinv[r];
      float dq = dv * q[r];
      float u0 = acc[i][0] * dv + dq * cc.x + bb.x;
      float u1 = acc[i][1] * dv + dq * cc.y + bb.y;
      float u2 = acc[i][2] * dv + dq * cc.z + bb.z;
      float u3 = acc[i][3] * dv + dq * cc.w + bb.w;
      float o0 = u0 >= 0.f ? u0 : NEG_SLOPE * u0;
      float o1 = u1 >= 0.f ? u1 : NEG_SLOPE * u1;
      float o2 = u2 >= 0.f ? u2 : NEG_SLOPE * u2;
      float o3 = u3 >= 0.f ? u3 : NEG_SLOPE * u3;
      float4 z = make_float4(o0 * dv, o1 * dv, o2 * dv, o3 * dv);
      *(float4*)(Z + (size_t)r * 64 + tc4) = z;
      s1[0] += o0; s2[0] += o0 * o0;
      s1[1] += o1; s2[1] += o1 * o1;
      s1[2] += o2; s2[2] += o2 * o2;
      s1[3] += o3; s2[3] += o3 * o3;
    }
  }
  __syncthreads();  // Ws no longer needed; reuse for BN reduction
  float (*red1)[64] = (float(*)[64]) & Ws[0][0];
  float (*red2)[64] = (float(*)[64]) & Ws[16][0];
#pragma unroll
  for (int j = 0; j < 4; ++j) {
    red1[tr][tc4 + j] = s1[j];
    red2[tr][tc4 + j] = s2[j];
  }
  __syncthreads();
  if (t < 64) {
    float a1 = 0.f, a2 = 0.f;
#pragma unroll
    for (int i = 0; i < 16; ++i) {
      a1 += red1[i][t];
      a2 += red2[i][t];
    }
    atomicAdd(&bnsOut[t], a1);
    atomicAdd(&bnsOut[64 + t], a2);
  }
}

// Weight-stationary MFMA head. Grid (64, 12): block owns one 128-col chunk
// (y: 0-5 mu, 6-11 ls), loads its 32 W-frags once (A operand), strides over
// 64-row tiles (wave = 16 rows). mfma(W, G) -> D[wcol][grow]: lane holds
// 4 consecutive cols of ONE row -> float4 stores. No LDS, no barriers.
__global__ __launch_bounds__(256) void head_mfma2(
    const u16* __restrict__ Ghi, const u16* __restrict__ Glo,
    const float* __restrict__ dinv, const float* __restrict__ q,
    const u16* __restrict__ Bh, const u16* __restrict__ Bl,
    const float* __restrict__ cmu, const float* __restrict__ bmu,
    const float* __restrict__ cls, const float* __restrict__ bls,
    float* __restrict__ OUT, int N, int ntiles) {
  const int t = threadIdx.x;
  const int w = t >> 6, l = t & 63;
  const int yy = blockIdx.y;
  const int head = (yy >= 6) ? 1 : 0;
  const int cc = head ? yy - 6 : yy;
  const int c0 = cc * 128;
  const float* cx = head ? cls : cmu;
  const float* bb = head ? bls : bmu;
  float* O = OUT + (head ? (size_t)N * 768 : 0);

  const size_t base = (size_t)(head * 6 + cc) * 2 * 8 * 64 * 8;
  const u16* bhp = Bh + base;
  const u16* blp = Bl + base;
  bf16x8 wh[8][2], wl[8][2];
#pragma unroll
  for (int ct = 0; ct < 8; ++ct) {
    wh[ct][0] = *(const bf16x8*)(bhp + (((size_t)ct) * 64 + l) * 8);
    wh[ct][1] = *(const bf16x8*)(bhp + (((size_t)(8 + ct)) * 64 + l) * 8);
    wl[ct][0] = *(const bf16x8*)(blp + (((size_t)ct) * 64 + l) * 8);
    wl[ct][1] = *(const bf16x8*)(blp + (((size_t)(8 + ct)) * 64 + l) * 8);
  }

  const int colb = c0 + ((l >> 4) << 2);
  for (int tile = blockIdx.x; tile < ntiles; tile += gridDim.x) {
    const int grow = tile * 64 + w * 16 + (l & 15);
    const int gc = grow < N ? grow : N - 1;
    const u16* gh = Ghi + (size_t)gc * 64 + ((l >> 4) << 3);
    const u16* gl = Glo + (size_t)gc * 64 + ((l >> 4) << 3);
    const bf16x8 gh0 = *(const bf16x8*)gh;
    const bf16x8 gh1 = *(const bf16x8*)(gh + 32);
    const bf16x8 gl0 = *(const bf16x8*)gl;
    const bf16x8 gl1 = *(const bf16x8*)(gl + 32);
    const float dv = dinv[gc];
    const float dq = dv * q[gc];

#pragma unroll
    for (int ct = 0; ct < 8; ++ct) {
      f32x4 a = {0.f, 0.f, 0.f, 0.f};
      a = __builtin_amdgcn_mfma_f32_16x16x32_bf16(wh[ct][0], gh0, a, 0, 0, 0);
      a = __builtin_amdgcn_mfma_f32_16x16x32_bf16(wh[ct][1], gh1, a, 0, 0, 0);
      a = __builtin_amdgcn_mfma_f32_16x16x32_bf16(wl[ct][0], gh0, a, 0, 0, 0);
      a = __builtin_amdgcn_mfma_f32_16x16x32_bf16(wl[ct][1], gh1, a, 0, 0, 0);
      a = __builtin_amdgcn_mfma_f32_16x16x32_bf16(wh[ct][0], gl0, a, 0, 0, 0);
      a = __builtin_amdgcn_mfma_f32_16x16x32_bf16(wh[ct][1], gl1, a, 0, 0, 0);
      if (grow < N) {
        int col = colb + ct * 16;
        float4 cxv = *(const float4*)(cx + col);
        float4 bbv = *(const float4*)(bb + col);
        float4 o = make_float4(a[0] * dv + dq * cxv.x + bbv.x,
                               a[1] * dv + dq * cxv.y + bbv.y,
                               a[2] * dv + dq * cxv.z + bbv.z,
                               a[3] * dv + dq * cxv.w + bbv.w);
        *(float4*)(O + (size_t)grow * 768 + col) = o;
      }
    }
  }
}

extern "C" void kernel_launch(void* const* d_in, const int* in_sizes, int n_in,
                              void* d_out, int out_size, void* d_ws, size_t ws_size,
                              hipStream_t stream) {
  const float* x   = (const float*)d_in[0];
  const int*   ei  = (const int*)d_in[1];
  const float* W1  = (const float*)d_in[2];
  const float* b1  = (const float*)d_in[3];
  const float* g1  = (const float*)d_in[4];
  const float* be1 = (const float*)d_in[5];
  const float* W2  = (const float*)d_in[6];
  const float* b2  = (const float*)d_in[7];
  const float* g2  = (const float*)d_in[8];
  const float* be2 = (const float*)d_in[9];
  const float* W3  = (const float*)d_in[10];
  const float* b3  = (const float*)d_in[11];
  const float* g3  = (const float*)d_in[12];
  const float* be3 = (const float*)d_in[13];
  const float* Wmu = (const float*)d_in[14];
  const float* bmu = (const float*)d_in[15];
  const float* Wls = (const float*)d_in[16];
  const float* bls = (const float*)d_in[17];

  const int N = in_sizes[0] / 3;
  const int E = in_sizes[1] / 2;
  const int* src = ei;
  const int* dst = ei + E;
  float* out = (float*)d_out;

  char* ws = (char*)d_ws;
  size_t o = 0;
  float* dinv = (float*)(ws + o); o += (size_t)N * 4;
  float* qv   = (float*)(ws + o); o += (size_t)N * 4;
  float* bns  = (float*)(ws + o); o += 384 * 4;
  float4* xd  = (float4*)(ws + o); o += (size_t)N * 16;
  u16* Bh     = (u16*)(ws + o);   o += (size_t)12 * 2 * 8 * 64 * 8 * 2;
  u16* Bl     = (u16*)(ws + o);   o += (size_t)12 * 2 * 8 * 64 * 8 * 2;
  float* cmu  = (float*)(ws + o); o += 768 * 4;
  float* cls  = (float*)(ws + o); o += 768 * 4;
  u16* Ghi    = (u16*)(ws + o);   o += (size_t)N * 64 * 2;
  u16* Glo    = (u16*)(ws + o);   o += (size_t)N * 64 * 2;
  int* cnt    = (int*)(ws + o);   o += (size_t)N * 4;
  int* rowptr = (int*)(ws + o);   o += ((size_t)N + 1) * 4;
  int* cursor = (int*)(ws + o);   o += (size_t)N * 4;
  int* bsum   = (int*)(ws + o);   o += 64 * 4;
  int* eidx   = (int*)(ws + o);   o += (size_t)E * 4;
  float* B0   = (float*)(ws + o); o += (size_t)N * 64 * 4;
  float* B1   = (float*)(ws + o); o += (size_t)N * 64 * 4;
  // ws_size observed ~1.2 GB; total used ~46 MB.

  const float invN = 1.0f / (float)N;
  int nbN = (N + 255) / 256;
  int nbE = (E + 255) / 256;
  int gb  = (N + 63) / 64;
  int wb  = (N + 3) / 4;
  int sbA = (N + 1023) / 1024;

  // CSR build (edge_index constant across all 4 propagations)
  init_k<<<nbN, 256, 0, stream>>>(cnt, bns, N);
  hist_k<<<nbE, 256, 0, stream>>>(dst, cnt, E);
  scanA<<<sbA, 1024, 0, stream>>>(cnt, rowptr, bsum, N);
  scanB<<<1, 64, 0, stream>>>(bsum, sbA);
  scanC<<<nbN, 256, 0, stream>>>(cnt, rowptr, cursor, bsum, x, dinv, xd, N, E);
  fill_k<<<nbE, 256, 0, stream>>>(src, dst, cursor, eidx, E);

  // ---- layer 1: fused gather(xd float4)+GEMM+stats, writes Z1=B0 and q ----
  l1_fused<<<1024, 256, 0, stream>>>(rowptr, eidx, xd, W1, b1, B0, qv, bns, N);

  // ---- layer 2 (split gather -> GEMM w/ integrated prep) ----
  gather64<<<wb, 256, 0, stream>>>(rowptr, eidx, B0, B1, N);      // B1 = G1
  gemm_bnq2<<<gb, 256, 0, stream>>>(B1, dinv, qv, W2, g1, be1, bns + 0, b2,
                                    B0, bns + 128, invN, N);

  // ---- layer 3 ----
  gather64<<<wb, 256, 0, stream>>>(rowptr, eidx, B0, B1, N);      // B1 = G2
  gemm_bnq2<<<gb, 256, 0, stream>>>(B1, dinv, qv, W3, g2, be2, bns + 128, b3,
                                    B0, bns + 256, invN, N);
  prep_head<<<12, 256, 0, stream>>>(bns + 256, g3, be3, Wmu, Wls, Bh, Bl, cmu, cls, invN);

  // ---- final propagate (split-bf16 output) + weight-stationary MFMA head ----
  gather64h<<<wb, 256, 0, stream>>>(rowptr, eidx, B0, Ghi, Glo, N);
  dim3 hgrid(64, 12);
  head_mfma2<<<hgrid, 256, 0, stream>>>(Ghi, Glo, dinv, qv, Bh, Bl,
                                        cmu, bmu, cls, bls, out, N, gb);
}